// Round 2
// baseline (386.381 us; speedup 1.0000x reference)
//
#include <hip/hip_runtime.h>
#include <stdint.h>

typedef __attribute__((ext_vector_type(8))) short short8;
typedef __attribute__((ext_vector_type(4))) short short4v;
typedef __attribute__((ext_vector_type(4))) float float4v;
typedef __attribute__((ext_vector_type(2))) unsigned uint2v;

__device__ __forceinline__ float bf2f(short s) {
  union { unsigned u; float f; } x;
  x.u = ((unsigned)(unsigned short)s) << 16;
  return x.f;
}
__device__ __forceinline__ short f2bf(float f) {
  union { float f; unsigned u; } x;
  x.f = f;
  unsigned r = x.u + 0x7fffu + ((x.u >> 16) & 1u);
  return (short)(r >> 16);
}
// bare v_exp_f32 — exp2f() calls __ocml_exp2_f32 (range/denorm fixups, ~30
// VALU); our scores are bounded |s|<~50 so the raw HW op is exact.
__device__ __forceinline__ float fexp2(float x) {
#if __has_builtin(__builtin_amdgcn_exp2f)
  return __builtin_amdgcn_exp2f(x);
#else
  float r;
  asm("v_exp_f32 %0, %1" : "=v"(r) : "v"(x));
  return r;
#endif
}
__device__ __forceinline__ void glds16(const void* g, void* l) {
  __builtin_amdgcn_global_load_lds(
      (const __attribute__((address_space(1))) void*)g,
      (__attribute__((address_space(3))) void*)l, 16, 0, 0);
}
// raw barrier: no compiler-inserted vmcnt(0) drain (that drain is the m97
// structural stall); sched_barrier(0) pins instruction order around it.
__device__ __forceinline__ void sbar() {
  __builtin_amdgcn_sched_barrier(0);
  __builtin_amdgcn_s_barrier();
  __builtin_amdgcn_sched_barrier(0);
}

// ---------------------------------------------------------------------------
// fp32 -> bf16 elementwise, 8 elems/thread.
// ---------------------------------------------------------------------------
__global__ __launch_bounds__(256) void f32_to_bf16(const float* __restrict__ s,
                                                   short* __restrict__ d) {
  const long i = ((long)blockIdx.x * 256 + threadIdx.x) * 8;
  const float4v a = *(const float4v*)&s[i];
  const float4v b = *(const float4v*)&s[i + 4];
  short8 v;
#pragma unroll
  for (int e = 0; e < 4; ++e) { v[e] = f2bf(a[e]); v[e + 4] = f2bf(b[e]); }
  *(short8*)&d[i] = v;
}

// ---------------------------------------------------------------------------
// fp32 transpose -> bf16: src (R x C, f32) -> dst (C x R, bf16), 64x64 tiles.
// ---------------------------------------------------------------------------
__device__ __forceinline__ void transpose_tile(
    const float* __restrict__ src, short* __restrict__ dst, int R, int C,
    int r0, int c0) {
  __shared__ short t[64 * 72];
  const int tid = threadIdx.x;
#pragma unroll
  for (int r = 0; r < 2; ++r) {
    int c = r * 256 + tid;
    int row = c >> 3, col8 = (c & 7) * 8;
    const float4v a = *(const float4v*)&src[(long)(r0 + row) * C + c0 + col8];
    const float4v b = *(const float4v*)&src[(long)(r0 + row) * C + c0 + col8 + 4];
    short8 v;
#pragma unroll
    for (int e = 0; e < 4; ++e) { v[e] = f2bf(a[e]); v[e + 4] = f2bf(b[e]); }
    *(short8*)&t[row * 72 + col8] = v;
  }
  __syncthreads();
#pragma unroll
  for (int r = 0; r < 2; ++r) {
    int c = r * 256 + tid;
    int orow = c >> 3, ocol8 = (c & 7) * 8;
    short8 w;
#pragma unroll
    for (int e = 0; e < 8; ++e) w[e] = t[(ocol8 + e) * 72 + orow];
    *(short8*)&dst[(long)(c0 + orow) * R + r0 + ocol8] = w;
  }
}

__global__ __launch_bounds__(256) void transpose_f2b(
    const float* __restrict__ src, short* __restrict__ dst, int R, int C) {
  transpose_tile(src, dst, R, C, blockIdx.y * 64, blockIdx.x * 64);
}

// Fused QKV weight transpose: z=0 Wq (C=2048), z=1 Wk, z=2 Wv (C=512).
__global__ __launch_bounds__(256) void wtrans3(
    const float* __restrict__ Wq, const float* __restrict__ Wk,
    const float* __restrict__ Wv, short* __restrict__ WT) {
  const int z = blockIdx.z;
  const float* src = z == 0 ? Wq : (z == 1 ? Wk : Wv);
  const int C = z == 0 ? 2048 : 512;
  if (blockIdx.x * 64 >= C) return;
  short* dst = WT + (z == 0 ? 0 : (z == 1 ? 2048 * 2048 : 2560 * 2048));
  transpose_tile(src, dst, 2048, C, blockIdx.y * 64, blockIdx.x * 64);
}

// ---------------------------------------------------------------------------
// V reshape+transpose: Y (B,S,ld) cols [col0, col0+512) bf16 -> Vt (B,G,64,S).
// grid: (S/64, B*G)
// ---------------------------------------------------------------------------
__global__ __launch_bounds__(256) void vtrans(const short* __restrict__ Y,
                                              short* __restrict__ Vt,
                                              int ld, int col0) {
  const int bg = blockIdx.y;
  const int b = bg >> 3, gk = bg & 7;
  const int s0 = blockIdx.x * 64;
  __shared__ short t[64 * 72];
  const int tid = threadIdx.x;
#pragma unroll
  for (int r = 0; r < 2; ++r) {
    int c = r * 256 + tid;
    int row = c >> 3, col8 = (c & 7) * 8;
    short8 v = *(const short8*)&Y[(long)(b * 2048 + s0 + row) * ld + col0 + gk * 64 + col8];
    *(short8*)&t[row * 72 + col8] = v;
  }
  __syncthreads();
#pragma unroll
  for (int r = 0; r < 2; ++r) {
    int c = r * 256 + tid;
    int d = c >> 3, s8 = (c & 7) * 8;
    short8 w;
#pragma unroll
    for (int e = 0; e < 8; ++e) w[e] = t[(s8 + e) * 72 + d];
    *(short8*)&Vt[((long)bg * 64 + d) * 2048 + s0 + s8] = w;
  }
}

// ---------------------------------------------------------------------------
// RoPE + layout change: Y (B,S,ld) cols [col0, col0+NH*64) -> out (B,NH,S,64).
// ---------------------------------------------------------------------------
__global__ __launch_bounds__(256) void rope_kernel(
    const short* __restrict__ Y, const float* __restrict__ cosp,
    const float* __restrict__ sinp, short* __restrict__ out,
    int NH, int lgNH, int ld, int col0, float scale) {
  const long tid = (long)blockIdx.x * 256 + threadIdx.x;
  const int d = (int)(tid & 31);
  const long t1 = tid >> 5;
  const int h = (int)(t1 & (NH - 1));
  const long t2 = t1 >> lgNH;
  const int s = (int)(t2 & 2047);
  const int b = (int)(t2 >> 11);
  const long ib = (long)(b * 2048 + s) * ld + col0 + h * 64 + d;
  const float x1 = bf2f(Y[ib]);
  const float x2 = bf2f(Y[ib + 32]);
  const float c1 = cosp[s * 64 + d];
  const float c2 = cosp[s * 64 + d + 32];
  const float s1 = sinp[s * 64 + d];
  const float s2 = sinp[s * 64 + d + 32];
  const long ob = ((long)(b * NH + h) * 2048 + s) * 64 + d;
  out[ob] = f2bf((x1 * c1 - x2 * s1) * scale);
  out[ob + 32] = f2bf((x2 * c2 + x1 * s2) * scale);
}

// ---------------------------------------------------------------------------
// GEMM, 256x256 tile, BK=64, 8 waves (2M x 4N), 8-phase-style schedule:
//   C (MxN) = A (MxK,bf16) * BT (NxK,bf16)^T, OutT = short(bf16) or float.
// - double-buffered 256x64 K-tiles for A and B (128 KiB STATIC LDS — the
//   dynamic-shmem+hipFuncSetAttribute path fails at launch on ROCm; static
//   group-segment size is validated against the 160 KiB HW limit instead)
// - st_16x32 LDS swizzle (col ^= ((row>>2)&1)<<4), applied as pre-swizzled
//   global SOURCE + swizzled ds_read (glds16 dest must stay linear)
// - 4 phases per K-tile: quadrants (mh,nh) = (0,0),(0,1),(1,1),(1,0);
//   ds-read pattern 12/4/8/0 (A reloaded per mh, both B halves held in regs)
// - prefetch tile t+2 into the buffer being read, each region staged only
//   after the trailing barrier of the phase that last reads it:
//     ph1: A rows {0-63,128-191}; ph2: all B; ph3: A rows {64-127,192-255}
// - boundary s_waitcnt vmcnt(8): this tile's 8 prefetch loads stay in flight
//   across the barrier; tile t+1's loads (issued a full tile ago) are landed.
// ---------------------------------------------------------------------------
template <typename OutT>
__global__ __launch_bounds__(512, 2) void gemm256(
    const short* __restrict__ A, const short* __restrict__ BT,
    OutT* __restrict__ C, int M, int N, int K) {
  (void)M;
  __shared__ short As[2][16384];  // [buf][256 rows x 64 cols]
  __shared__ short Bs[2][16384];
  const int tid = threadIdx.x;
  const int w = tid >> 6, lane = tid & 63;
  const int g = lane >> 4, lr = lane & 15;
  const int wm = w >> 2, wn = w & 3;
  const int m0 = blockIdx.y << 8, n0 = blockIdx.x << 8;

  // staging: load l covers rows [l*64, l*64+64); thread row r0 = tid>>3,
  // col8 = (tid&7)*8; source col pre-swizzled (same involution as the read).
  const int r0 = tid >> 3;
  const int scol = ((tid & 7) << 3) ^ (((r0 >> 2) & 1) << 4);
  const long aoff = (long)(m0 + r0) * K + scol;
  const long boff = (long)(n0 + r0) * K + scol;

  // ds_read offsets (element units); swizzle bit depends only on lr>>2.
  const int swz = ((lr >> 2) & 1) << 4;
  const int acol0 = (g << 3) ^ swz;         // kk = 0
  const int acol1 = (32 + (g << 3)) ^ swz;  // kk = 1
  const int abase = (wm * 128 + lr) * 64;
  const int bbase = (wn * 64 + lr) * 64;

  float4v acc[8][4];
#pragma unroll
  for (int i = 0; i < 8; ++i)
#pragma unroll
    for (int j = 0; j < 4; ++j) acc[i][j] = (float4v)0.f;

#define STAGE_A(l, buf, kg)                                          \
  glds16(A + aoff + (long)(l) * 64 * K + (kg),                       \
         &As[(buf)][(l) * 4096 + w * 512])
#define STAGE_B(l, buf, kg)                                          \
  glds16(BT + boff + (long)(l) * 64 * K + (kg),                      \
         &Bs[(buf)][(l) * 4096 + w * 512])

  const int NT = K >> 6;
  // prologue: tile 0 -> buf0 (8 loads), tile 1 -> buf1 (8 loads)
#pragma unroll
  for (int l = 0; l < 4; ++l) { STAGE_A(l, 0, 0); STAGE_B(l, 0, 0); }
#pragma unroll
  for (int l = 0; l < 4; ++l) { STAGE_A(l, 1, 64); STAGE_B(l, 1, 64); }
  asm volatile("s_waitcnt vmcnt(8)" ::: "memory");  // tile 0 landed
  sbar();

  short8 aR[4][2], bR0[2][2], bR1[2][2];

#define LDA(MH, ASB)                                                       \
  _Pragma("unroll") for (int i = 0; i < 4; ++i) {                          \
    aR[i][0] = *(const short8*)&ASB[abase + ((MH)*4 + i) * 1024 + acol0];  \
    aR[i][1] = *(const short8*)&ASB[abase + ((MH)*4 + i) * 1024 + acol1];  \
  }
#define LDB(NH, BSB, BR)                                                   \
  _Pragma("unroll") for (int j = 0; j < 2; ++j) {                          \
    BR[j][0] = *(const short8*)&BSB[bbase + ((NH)*2 + j) * 1024 + acol0];  \
    BR[j][1] = *(const short8*)&BSB[bbase + ((NH)*2 + j) * 1024 + acol1];  \
  }
#define MMA_Q(MH, NH, BR)                                                  \
  __builtin_amdgcn_s_setprio(1);                                           \
  _Pragma("unroll") for (int kk = 0; kk < 2; ++kk)                         \
  _Pragma("unroll") for (int i = 0; i < 4; ++i)                            \
  _Pragma("unroll") for (int j = 0; j < 2; ++j)                            \
    acc[(MH)*4 + i][(NH)*2 + j] = __builtin_amdgcn_mfma_f32_16x16x32_bf16( \
        aR[i][kk], BR[j][kk], acc[(MH)*4 + i][(NH)*2 + j], 0, 0, 0);       \
  __builtin_amdgcn_s_setprio(0);

  for (int t = 0; t < NT; ++t) {
    const short* const Asb = As[t & 1];
    const short* const Bsb = Bs[t & 1];
    const long kg = (long)(t + 2) << 6;
    const bool pre = (t + 2) < NT;

    // phase 0: quadrant (0,0)
    LDA(0, Asb);
    LDB(0, Bsb, bR0);
    sbar();
    MMA_Q(0, 0, bR0);
    sbar();
    // phase 1: (0,1); prefetch A halves 0,2 of t+2 (rows consumed in ph0)
    LDB(1, Bsb, bR1);
    if (pre) { STAGE_A(0, t & 1, kg); STAGE_A(2, t & 1, kg); }
    sbar();
    MMA_Q(0, 1, bR1);
    sbar();
    // phase 2: (1,1); prefetch all B of t+2 (B fully consumed after ph1)
    LDA(1, Asb);
    if (pre) {
      STAGE_B(0, t & 1, kg); STAGE_B(1, t & 1, kg);
      STAGE_B(2, t & 1, kg); STAGE_B(3, t & 1, kg);
    }
    sbar();
    MMA_Q(1, 1, bR1);
    sbar();
    // phase 3: (1,0); prefetch A halves 1,3 (rows consumed in ph2)
    if (pre) { STAGE_A(1, t & 1, kg); STAGE_A(3, t & 1, kg); }
    sbar();
    MMA_Q(1, 0, bR0);
    // boundary: counted drain — keep this tile's 8 prefetch loads in flight
    __builtin_amdgcn_sched_barrier(0);
    if (pre) { asm volatile("s_waitcnt vmcnt(8)" ::: "memory"); }
    else     { asm volatile("s_waitcnt vmcnt(0)" ::: "memory"); }
    sbar();
  }

#pragma unroll
  for (int i = 0; i < 8; ++i)
#pragma unroll
    for (int j = 0; j < 4; ++j)
#pragma unroll
      for (int t4 = 0; t4 < 4; ++t4) {
        const int r = m0 + wm * 128 + i * 16 + g * 4 + t4;
        const int cc = n0 + wn * 64 + j * 16 + lr;
        const float v = acc[i][j][t4];
        if constexpr (sizeof(OutT) == 2)
          C[(long)r * N + cc] = f2bf(v);
        else
          C[(long)r * N + cc] = v;
      }
#undef STAGE_A
#undef STAGE_B
#undef LDA
#undef LDB
#undef MMA_Q
}

// ---------------------------------------------------------------------------
// Flash attention, transposed formulation, fixed-shift softmax.
// Qr (B,H,S,64) pre-scaled by log2(e)/8, Kr (B,G,S,64), Vt (B,G,64,S).
// Block: 512 thr (8 waves), 128 q x full S. S^T = K*Q^T, O^T = V^T*P^T.
// l(q) computed by an all-ones-A MFMA on the P fragments (no VALU reduction).
// ---------------------------------------------------------------------------
__global__ __launch_bounds__(512, 2) void attn_kernel(
    const short* __restrict__ Qr, const short* __restrict__ Kr,
    const short* __restrict__ Vt, short* __restrict__ Ctx) {
  constexpr int S = 2048;
  const int bh = blockIdx.y;
  const int b = bh >> 5, h = bh & 31;
  const int gk = h >> 2;
  const int q0 = blockIdx.x << 7;
  const int tid = threadIdx.x;
  const int w = tid >> 6, lane = tid & 63;
  const int g = lane >> 4, lr = lane & 15;
  const int b8 = lr & 7;
  const int qrow = w * 16 + lr;

  __shared__ short Ks[128 * 64];   // [kv][d], 8-short granule swizzle by kv&7
  __shared__ short Vs[64 * 128];   // [d][kv], granule swizzle by d&7
  __shared__ short Ps[128 * 128];  // [q][kv], granule swizzle by q&7

  const short* Qb = Qr + (long)(b * 32 + h) * S * 64;
  const short* KbIt = Kr + (long)(b * 8 + gk) * S * 64;
  const short* VbIt = Vt + (long)(b * 8 + gk) * 64 * S;

  // hoisted LDS element-offsets
  const int ko0 = lr * 64 + ((0 + g) ^ b8) * 8;  // Ks, kk=0; +i*1024
  const int ko1 = lr * 64 + ((4 + g) ^ b8) * 8;  // Ks, kk=1; +i*1024
  const int jv0 = g ^ b8;
  const int vo0 = lr * 128 + jv0 * 8;        // Vs, ks even; +di*2048+(ks>>1)*64
  const int vo1 = lr * 128 + (jv0 ^ 4) * 8;  // Vs, ks odd
  int pr[4], pw[8];
#pragma unroll
  for (int ks = 0; ks < 4; ++ks) pr[ks] = qrow * 128 + ((4 * ks + g) ^ b8) * 8;
#pragma unroll
  for (int i = 0; i < 8; ++i)
    pw[i] = qrow * 128 + ((2 * i + (g >> 1)) ^ b8) * 8 + (g & 1) * 4;

  // per-lane global element-offsets for the staging DMA
  long koff[2], voff[2];
#pragma unroll
  for (int r = 0; r < 2; ++r) {
    const int c = r * 512 + w * 64 + lane;
    const int kv = c >> 3, slot = c & 7;
    koff[r] = (long)kv * 64 + (slot ^ (kv & 7)) * 8;
    const int dd = c >> 4, s16 = c & 15;
    voff[r] = (long)dd * S + ((s16 & 8) | ((s16 & 7) ^ (dd & 7))) * 8;
  }

  short8 qf[2];
  qf[0] = *(const short8*)&Qb[(long)(q0 + qrow) * 64 + g * 8];
  qf[1] = *(const short8*)&Qb[(long)(q0 + qrow) * 64 + 32 + g * 8];

  const short8 ones = (short8)(short)0x3F80;  // bf16 1.0 x8
  float4v lacc = (float4v)0.f;
  float4v oacc[4];
#pragma unroll
  for (int di = 0; di < 4; ++di) oacc[di] = (float4v)0.f;

  for (int it = 0; it < 16; ++it) {
#pragma unroll
    for (int r = 0; r < 2; ++r) {
      const int cb = r * 512 + w * 64;
      glds16(KbIt + koff[r], Ks + cb * 8);
      glds16(VbIt + voff[r], Vs + cb * 8);
    }
    __syncthreads();

    // S^T tile: rows = kv (128), cols = q (wave strip of 16)
    float4v sacc[8];
#pragma unroll
    for (int i = 0; i < 8; ++i) sacc[i] = (float4v)0.f;
#pragma unroll
    for (int i = 0; i < 8; ++i) {
      const short8 a0 = *(const short8*)&Ks[ko0 + i * 1024];
      sacc[i] = __builtin_amdgcn_mfma_f32_16x16x32_bf16(a0, qf[0], sacc[i], 0, 0, 0);
    }
#pragma unroll
    for (int i = 0; i < 8; ++i) {
      const short8 a1 = *(const short8*)&Ks[ko1 + i * 1024];
      sacc[i] = __builtin_amdgcn_mfma_f32_16x16x32_bf16(a1, qf[1], sacc[i], 0, 0, 0);
    }

    // fixed-shift softmax: p = exp2(s) (bare v_exp_f32), pack bf16 -> Ps
#pragma unroll
    for (int i = 0; i < 8; ++i) {
      union { float f; unsigned u; } a0, a1, a2, a3;
      a0.f = fexp2(sacc[i][0]);
      a1.f = fexp2(sacc[i][1]);
      a2.f = fexp2(sacc[i][2]);
      a3.f = fexp2(sacc[i][3]);
      const unsigned d0 = __builtin_amdgcn_perm(a1.u + 0x8000u, a0.u + 0x8000u, 0x07060302u);
      const unsigned d1 = __builtin_amdgcn_perm(a3.u + 0x8000u, a2.u + 0x8000u, 0x07060302u);
      *(uint2v*)&Ps[pw[i]] = (uint2v){d0, d1};
    }

    // O^T += V^T * P^T; l += 1^T * P^T (Ps rows wave-private; no barrier)
#pragma unroll
    for (int ks = 0; ks < 4; ++ks) {
      const short8 pf = *(const short8*)&Ps[pr[ks]];
      const int vbase = (ks & 1) ? vo1 : vo0;
      lacc = __builtin_amdgcn_mfma_f32_16x16x32_bf16(ones, pf, lacc, 0, 0, 0);
#pragma unroll
      for (int di = 0; di < 4; ++di) {
        const short8 vf = *(const short8*)&Vs[vbase + di * 2048 + (ks >> 1) * 64];
        oacc[di] = __builtin_amdgcn_mfma_f32_16x16x32_bf16(vf, pf, oacc[di], 0, 0, 0);
      }
    }
    __syncthreads();
    KbIt += 128 * 64;
    VbIt += 128;
  }

  // all-ones A => every C row/reg of lacc equals l(q=lr)
  const float inv = 1.f / lacc[0];

  const int q = q0 + qrow;
#pragma unroll
  for (int di = 0; di < 4; ++di) {
    short4v o;
#pragma unroll
    for (int t = 0; t < 4; ++t) o[t] = f2bf(oacc[di][t] * inv);
    *(short4v*)&Ctx[(long)(b * S + q) * 2048 + h * 64 + di * 16 + g * 4] = o;
  }
}

// ---------------------------------------------------------------------------
extern "C" void kernel_launch(void* const* d_in, const int* in_sizes, int n_in,
                              void* d_out, int out_size, void* d_ws, size_t ws_size,
                              hipStream_t stream) {
  (void)in_sizes; (void)n_in; (void)out_size; (void)ws_size;
  const float* X    = (const float*)d_in[0];
  const float* cosp = (const float*)d_in[2];
  const float* sinp = (const float*)d_in[3];
  const float* Wq   = (const float*)d_in[4];
  const float* Wk   = (const float*)d_in[5];
  const float* Wv   = (const float*)d_in[6];
  const float* Wo   = (const float*)d_in[7];
  float* out = (float*)d_out;
  char* ws = (char*)d_ws;

  short* Xb = (short*)(ws + 0);           // 16.8 MB bf16 X
  short* WT = (short*)(ws + 16777216);    // 12.6 MB fused QKV^T; reused for Wo^T
  short* Y  = (short*)(ws + 29360128);    // 25.2 MB fused QKV out; reused as Ctx
  short* Qr = (short*)(ws + 54525952);    // 16.8 MB
  short* Kr = (short*)(ws + 71303168);    // 4.2 MB
  short* Vt = (short*)(ws + 75497472);    // 4.2 MB  (total 79.7 MB)

  f32_to_bf16<<<4096, 256, 0, stream>>>(X, Xb);
  // fused QKV^T: rows [0,2048)=Wq^T, [2048,2560)=Wk^T, [2560,3072)=Wv^T
  wtrans3<<<dim3(32, 32, 3), 256, 0, stream>>>(Wq, Wk, Wv, WT);

  // fused QKV projection: Y (4096 x 3072), 256^2 tiles -> 12x16 = 192 blocks
  gemm256<short><<<dim3(12, 16), 512, 0, stream>>>(Xb, WT, Y, 4096, 3072, 2048);

  // Wo^T reuses WT (QKV GEMM already consumed it in stream order)
  transpose_f2b<<<dim3(32, 32), 256, 0, stream>>>(Wo, WT, 2048, 2048);

  // RoPE; Q pre-scaled by log2(e)/sqrt(hd) = log2(e)/8 for exp2-domain softmax
  rope_kernel<<<16384, 256, 0, stream>>>(Y, cosp, sinp, Qr, 32, 5, 3072, 0, 0.18033688011112043f);
  rope_kernel<<<4096, 256, 0, stream>>>(Y, cosp, sinp, Kr, 8, 3, 3072, 2048, 1.0f);
  vtrans<<<dim3(32, 16), 256, 0, stream>>>(Y, Vt, 3072, 2560);

  // attention -> Ctx (aliases Y, already consumed)
  attn_kernel<<<dim3(16, 64), 512, 0, stream>>>(Qr, Kr, Vt, Y);

  // output projection (fp32 out), 8x16 = 128 blocks
  gemm256<float><<<dim3(8, 16), 512, 0, stream>>>(Y, WT, out, 4096, 2048, 2048);
}

// Round 3
// 379.871 us; speedup vs baseline: 1.0171x; 1.0171x over previous
//
#include <hip/hip_runtime.h>
#include <stdint.h>

typedef __attribute__((ext_vector_type(8))) short short8;
typedef __attribute__((ext_vector_type(4))) short short4v;
typedef __attribute__((ext_vector_type(4))) float float4v;
typedef __attribute__((ext_vector_type(2))) unsigned uint2v;

__device__ __forceinline__ float bf2f(short s) {
  union { unsigned u; float f; } x;
  x.u = ((unsigned)(unsigned short)s) << 16;
  return x.f;
}
__device__ __forceinline__ short f2bf(float f) {
  union { float f; unsigned u; } x;
  x.f = f;
  unsigned r = x.u + 0x7fffu + ((x.u >> 16) & 1u);
  return (short)(r >> 16);
}
// bare v_exp_f32 — exp2f() calls __ocml_exp2_f32 (range/denorm fixups, ~30
// VALU); our scores are bounded |s|<~50 so the raw HW op is exact.
__device__ __forceinline__ float fexp2(float x) {
#if __has_builtin(__builtin_amdgcn_exp2f)
  return __builtin_amdgcn_exp2f(x);
#else
  float r;
  asm("v_exp_f32 %0, %1" : "=v"(r) : "v"(x));
  return r;
#endif
}
__device__ __forceinline__ void glds16(const void* g, void* l) {
  __builtin_amdgcn_global_load_lds(
      (const __attribute__((address_space(1))) void*)g,
      (__attribute__((address_space(3))) void*)l, 16, 0, 0);
}
// raw barrier: no compiler-inserted vmcnt(0) drain (that drain is the m97
// structural stall); sched_barrier(0) pins instruction order around it.
__device__ __forceinline__ void sbar() {
  __builtin_amdgcn_sched_barrier(0);
  __builtin_amdgcn_s_barrier();
  __builtin_amdgcn_sched_barrier(0);
}

// ---------------------------------------------------------------------------
// fp32 -> bf16 elementwise, 8 elems/thread.
// ---------------------------------------------------------------------------
__global__ __launch_bounds__(256) void f32_to_bf16(const float* __restrict__ s,
                                                   short* __restrict__ d) {
  const long i = ((long)blockIdx.x * 256 + threadIdx.x) * 8;
  const float4v a = *(const float4v*)&s[i];
  const float4v b = *(const float4v*)&s[i + 4];
  short8 v;
#pragma unroll
  for (int e = 0; e < 4; ++e) { v[e] = f2bf(a[e]); v[e + 4] = f2bf(b[e]); }
  *(short8*)&d[i] = v;
}

// ---------------------------------------------------------------------------
// fp32 transpose -> bf16: src (R x C, f32) -> dst (C x R, bf16), 64x64 tiles.
// ---------------------------------------------------------------------------
__device__ __forceinline__ void transpose_tile(
    const float* __restrict__ src, short* __restrict__ dst, int R, int C,
    int r0, int c0) {
  __shared__ short t[64 * 72];
  const int tid = threadIdx.x;
#pragma unroll
  for (int r = 0; r < 2; ++r) {
    int c = r * 256 + tid;
    int row = c >> 3, col8 = (c & 7) * 8;
    const float4v a = *(const float4v*)&src[(long)(r0 + row) * C + c0 + col8];
    const float4v b = *(const float4v*)&src[(long)(r0 + row) * C + c0 + col8 + 4];
    short8 v;
#pragma unroll
    for (int e = 0; e < 4; ++e) { v[e] = f2bf(a[e]); v[e + 4] = f2bf(b[e]); }
    *(short8*)&t[row * 72 + col8] = v;
  }
  __syncthreads();
#pragma unroll
  for (int r = 0; r < 2; ++r) {
    int c = r * 256 + tid;
    int orow = c >> 3, ocol8 = (c & 7) * 8;
    short8 w;
#pragma unroll
    for (int e = 0; e < 8; ++e) w[e] = t[(ocol8 + e) * 72 + orow];
    *(short8*)&dst[(long)(c0 + orow) * R + r0 + ocol8] = w;
  }
}

__global__ __launch_bounds__(256) void transpose_f2b(
    const float* __restrict__ src, short* __restrict__ dst, int R, int C) {
  transpose_tile(src, dst, R, C, blockIdx.y * 64, blockIdx.x * 64);
}

// Fused QKV weight transpose: z=0 Wq (C=2048), z=1 Wk, z=2 Wv (C=512).
__global__ __launch_bounds__(256) void wtrans3(
    const float* __restrict__ Wq, const float* __restrict__ Wk,
    const float* __restrict__ Wv, short* __restrict__ WT) {
  const int z = blockIdx.z;
  const float* src = z == 0 ? Wq : (z == 1 ? Wk : Wv);
  const int C = z == 0 ? 2048 : 512;
  if (blockIdx.x * 64 >= C) return;
  short* dst = WT + (z == 0 ? 0 : (z == 1 ? 2048 * 2048 : 2560 * 2048));
  transpose_tile(src, dst, 2048, C, blockIdx.y * 64, blockIdx.x * 64);
}

// ---------------------------------------------------------------------------
// V reshape+transpose: Y (B,S,ld) cols [col0, col0+512) bf16 -> Vt (B,G,64,S).
// grid: (S/64, B*G)
// ---------------------------------------------------------------------------
__global__ __launch_bounds__(256) void vtrans(const short* __restrict__ Y,
                                              short* __restrict__ Vt,
                                              int ld, int col0) {
  const int bg = blockIdx.y;
  const int b = bg >> 3, gk = bg & 7;
  const int s0 = blockIdx.x * 64;
  __shared__ short t[64 * 72];
  const int tid = threadIdx.x;
#pragma unroll
  for (int r = 0; r < 2; ++r) {
    int c = r * 256 + tid;
    int row = c >> 3, col8 = (c & 7) * 8;
    short8 v = *(const short8*)&Y[(long)(b * 2048 + s0 + row) * ld + col0 + gk * 64 + col8];
    *(short8*)&t[row * 72 + col8] = v;
  }
  __syncthreads();
#pragma unroll
  for (int r = 0; r < 2; ++r) {
    int c = r * 256 + tid;
    int d = c >> 3, s8 = (c & 7) * 8;
    short8 w;
#pragma unroll
    for (int e = 0; e < 8; ++e) w[e] = t[(s8 + e) * 72 + d];
    *(short8*)&Vt[((long)bg * 64 + d) * 2048 + s0 + s8] = w;
  }
}

// ---------------------------------------------------------------------------
// RoPE + layout change: Y (B,S,ld) cols [col0, col0+NH*64) -> out (B,NH,S,64).
// ---------------------------------------------------------------------------
__global__ __launch_bounds__(256) void rope_kernel(
    const short* __restrict__ Y, const float* __restrict__ cosp,
    const float* __restrict__ sinp, short* __restrict__ out,
    int NH, int lgNH, int ld, int col0, float scale) {
  const long tid = (long)blockIdx.x * 256 + threadIdx.x;
  const int d = (int)(tid & 31);
  const long t1 = tid >> 5;
  const int h = (int)(t1 & (NH - 1));
  const long t2 = t1 >> lgNH;
  const int s = (int)(t2 & 2047);
  const int b = (int)(t2 >> 11);
  const long ib = (long)(b * 2048 + s) * ld + col0 + h * 64 + d;
  const float x1 = bf2f(Y[ib]);
  const float x2 = bf2f(Y[ib + 32]);
  const float c1 = cosp[s * 64 + d];
  const float c2 = cosp[s * 64 + d + 32];
  const float s1 = sinp[s * 64 + d];
  const float s2 = sinp[s * 64 + d + 32];
  const long ob = ((long)(b * NH + h) * 2048 + s) * 64 + d;
  out[ob] = f2bf((x1 * c1 - x2 * s1) * scale);
  out[ob + 32] = f2bf((x2 * c2 + x1 * s2) * scale);
}

// ---------------------------------------------------------------------------
// GEMM, 256x256 tile, BK=64, 8 waves (2M x 4N), phase schedule with counted
// vmcnt. C (MxN) = A (MxK,bf16) * BT (NxK,bf16)^T.
// - 2-bit LDS swizzle: col ^= ((row>>2)&1)<<4 ^ ((row>>3)&1)<<5. Spreads each
//   b128 fragment read (which spans only a 64-B column range) across all 32
//   banks: 8 lanes per 16-B quad = conflict-free minimum. Applied as
//   pre-swizzled global SOURCE + swizzled ds_read (glds16 dest stays linear).
// - XCD-aware chunked block remap (nwg % 8 == 0 for both call sites): blocks
//   on one XCD share A-panels (2 MB -> L2-resident) instead of 16 panels.
// - 4 phases/K-tile, prefetch t+2 into the buffer being read; each region
//   staged only after the barrier that follows its last reader. Boundary
//   s_waitcnt vmcnt(8) retires exactly tile t+1's loads.
// ---------------------------------------------------------------------------
template <typename OutT>
__global__ __launch_bounds__(512, 2) void gemm256(
    const short* __restrict__ A, const short* __restrict__ BT,
    OutT* __restrict__ C, int M, int N, int K) {
  (void)M;
  __shared__ short As[2][16384];  // [buf][256 rows x 64 cols]
  __shared__ short Bs[2][16384];
  const int tid = threadIdx.x;
  const int w = tid >> 6, lane = tid & 63;
  const int g = lane >> 4, lr = lane & 15;
  const int wm = w >> 2, wn = w & 3;

  // XCD-aware chunked bijective remap (requires nwg % 8 == 0)
  const int nbx = gridDim.x;
  const int nwg = nbx * gridDim.y;
  const int bid = blockIdx.y * nbx + blockIdx.x;
  const int cpx = nwg >> 3;
  const int nbid = (bid & 7) * cpx + (bid >> 3);
  const int m0 = (nbid / nbx) << 8, n0 = (nbid % nbx) << 8;

  // staging: thread row r0 = tid>>3, col8 = (tid&7)*8; source col carries the
  // inverse (= same, involution) swizzle keyed on row bits 2,3.
  const int r0 = tid >> 3;
  const int scol = ((tid & 7) << 3) ^ (((r0 >> 2) & 1) << 4) ^ (((r0 >> 3) & 1) << 5);
  const long aoff = (long)(m0 + r0) * K + scol;
  const long boff = (long)(n0 + r0) * K + scol;

  // ds_read offsets (element units); row bits 2,3 within a 16-row MFMA block
  // are lr bits 2,3.
  const int swz = (((lr >> 2) & 1) << 4) | (((lr >> 3) & 1) << 5);
  const int acol0 = (g << 3) ^ swz;         // kk = 0
  const int acol1 = (32 + (g << 3)) ^ swz;  // kk = 1
  const int abase = (wm * 128 + lr) * 64;
  const int bbase = (wn * 64 + lr) * 64;

  float4v acc[8][4];
#pragma unroll
  for (int i = 0; i < 8; ++i)
#pragma unroll
    for (int j = 0; j < 4; ++j) acc[i][j] = (float4v)0.f;

#define STAGE_A(l, buf, kg)                                          \
  glds16(A + aoff + (long)(l) * 64 * K + (kg),                       \
         &As[(buf)][(l) * 4096 + w * 512])
#define STAGE_B(l, buf, kg)                                          \
  glds16(BT + boff + (long)(l) * 64 * K + (kg),                      \
         &Bs[(buf)][(l) * 4096 + w * 512])

  const int NT = K >> 6;
  // prologue: tile 0 -> buf0 (8 loads), tile 1 -> buf1 (8 loads)
#pragma unroll
  for (int l = 0; l < 4; ++l) { STAGE_A(l, 0, 0); STAGE_B(l, 0, 0); }
#pragma unroll
  for (int l = 0; l < 4; ++l) { STAGE_A(l, 1, 64); STAGE_B(l, 1, 64); }
  asm volatile("s_waitcnt vmcnt(8)" ::: "memory");  // tile 0 landed
  sbar();

  short8 aR[4][2], bR0[2][2], bR1[2][2];

#define LDA(MH, ASB)                                                       \
  _Pragma("unroll") for (int i = 0; i < 4; ++i) {                          \
    aR[i][0] = *(const short8*)&ASB[abase + ((MH)*4 + i) * 1024 + acol0];  \
    aR[i][1] = *(const short8*)&ASB[abase + ((MH)*4 + i) * 1024 + acol1];  \
  }
#define LDB(NH, BSB, BR)                                                   \
  _Pragma("unroll") for (int j = 0; j < 2; ++j) {                          \
    BR[j][0] = *(const short8*)&BSB[bbase + ((NH)*2 + j) * 1024 + acol0];  \
    BR[j][1] = *(const short8*)&BSB[bbase + ((NH)*2 + j) * 1024 + acol1];  \
  }
#define MMA_Q(MH, NH, BR)                                                  \
  __builtin_amdgcn_s_setprio(1);                                           \
  _Pragma("unroll") for (int kk = 0; kk < 2; ++kk)                         \
  _Pragma("unroll") for (int i = 0; i < 4; ++i)                            \
  _Pragma("unroll") for (int j = 0; j < 2; ++j)                            \
    acc[(MH)*4 + i][(NH)*2 + j] = __builtin_amdgcn_mfma_f32_16x16x32_bf16( \
        aR[i][kk], BR[j][kk], acc[(MH)*4 + i][(NH)*2 + j], 0, 0, 0);       \
  __builtin_amdgcn_s_setprio(0);

  for (int t = 0; t < NT; ++t) {
    const short* const Asb = As[t & 1];
    const short* const Bsb = Bs[t & 1];
    const long kg = (long)(t + 2) << 6;
    const bool pre = (t + 2) < NT;

    // phase 0: quadrant (0,0)
    LDA(0, Asb);
    LDB(0, Bsb, bR0);
    sbar();
    MMA_Q(0, 0, bR0);
    sbar();
    // phase 1: (0,1); prefetch A halves 0,2 of t+2 (rows consumed in ph0)
    LDB(1, Bsb, bR1);
    if (pre) { STAGE_A(0, t & 1, kg); STAGE_A(2, t & 1, kg); }
    sbar();
    MMA_Q(0, 1, bR1);
    sbar();
    // phase 2: (1,1); prefetch all B of t+2 (B fully consumed after ph1)
    LDA(1, Asb);
    if (pre) {
      STAGE_B(0, t & 1, kg); STAGE_B(1, t & 1, kg);
      STAGE_B(2, t & 1, kg); STAGE_B(3, t & 1, kg);
    }
    sbar();
    MMA_Q(1, 1, bR1);
    sbar();
    // phase 3: (1,0); prefetch A halves 1,3 (rows consumed in ph2)
    if (pre) { STAGE_A(1, t & 1, kg); STAGE_A(3, t & 1, kg); }
    sbar();
    MMA_Q(1, 0, bR0);
    // boundary: counted drain — keep this tile's 8 prefetch loads in flight
    __builtin_amdgcn_sched_barrier(0);
    if (pre) { asm volatile("s_waitcnt vmcnt(8)" ::: "memory"); }
    else     { asm volatile("s_waitcnt vmcnt(0)" ::: "memory"); }
    sbar();
  }

#pragma unroll
  for (int i = 0; i < 8; ++i)
#pragma unroll
    for (int j = 0; j < 4; ++j)
#pragma unroll
      for (int t4 = 0; t4 < 4; ++t4) {
        const int r = m0 + wm * 128 + i * 16 + g * 4 + t4;
        const int cc = n0 + wn * 64 + j * 16 + lr;
        const float v = acc[i][j][t4];
        if constexpr (sizeof(OutT) == 2)
          C[(long)r * N + cc] = f2bf(v);
        else
          C[(long)r * N + cc] = v;
      }
#undef STAGE_A
#undef STAGE_B
#undef LDA
#undef LDB
#undef MMA_Q
}

// ---------------------------------------------------------------------------
// Flash attention, transposed formulation, fixed-shift softmax.
// Qr (B,H,S,64) pre-scaled by log2(e)/8, Kr (B,G,S,64), Vt (B,G,64,S).
// Block: 512 thr (8 waves), 128 q x full S. S^T = K*Q^T, O^T = V^T*P^T.
// KVBLK=64, 32 iterations, double-buffered K/V staging (raw barriers +
// counted vmcnt(2): issue it+1's 2 DMA loads, wait only for it's). LDS
// 48 KiB -> 3 blocks/CU. l(q) via all-ones-A MFMA (no VALU reduction).
// ---------------------------------------------------------------------------
__global__ __launch_bounds__(512, 6) void attn_kernel(
    const short* __restrict__ Qr, const short* __restrict__ Kr,
    const short* __restrict__ Vt, short* __restrict__ Ctx) {
  constexpr int S = 2048;
  constexpr int NIT = 32;
  const int bh = blockIdx.y;
  const int b = bh >> 5, h = bh & 31;
  const int gk = h >> 2;
  const int q0 = blockIdx.x << 7;
  const int tid = threadIdx.x;
  const int w = tid >> 6, lane = tid & 63;
  const int g = lane >> 4, lr = lane & 15;
  const int b8 = lr & 7;
  const int qrow = w * 16 + lr;

  __shared__ short Ks[2][64 * 64];  // [buf][kv][d], granule swizzle by kv&7
  __shared__ short Vs[2][64 * 64];  // [buf][d][kv], granule swizzle by d&7
  __shared__ short Ps[128 * 64];    // [q][kv],      granule swizzle by q&7

  const short* Qb = Qr + (long)(b * 32 + h) * S * 64;
  const short* Kb = Kr + (long)(b * 8 + gk) * S * 64;
  const short* Vb = Vt + (long)(b * 8 + gk) * 64 * S;

  // LDS read element-offsets
  const int ko0 = lr * 64 + ((0 + g) ^ b8) * 8;  // Ks, kk=0; +i*1024, i<4
  const int ko1 = lr * 64 + ((4 + g) ^ b8) * 8;  // Ks, kk=1
  int vo[2], pr[2], pw[4];
#pragma unroll
  for (int ks = 0; ks < 2; ++ks) {
    vo[ks] = lr * 64 + ((ks * 4 + g) ^ b8) * 8;    // Vs; +di*1024
    pr[ks] = qrow * 64 + ((ks * 4 + g) ^ b8) * 8;  // Ps read
  }
#pragma unroll
  for (int i = 0; i < 4; ++i)
    pw[i] = qrow * 64 + ((2 * i + (g >> 1)) ^ b8) * 8 + (g & 1) * 4;

  // staging: one glds16 each for K and V per iteration (8 KB each).
  // thread covers LDS row tid>>3, granule tid&7; global col pre-swizzled.
  const int srow = tid >> 3, sl = tid & 7;
  const long koff = (long)srow * 64 + (sl ^ (srow & 7)) * 8;
  const long voff = (long)srow * S + (sl ^ (srow & 7)) * 8;

  short8 qf[2];
  qf[0] = *(const short8*)&Qb[(long)(q0 + qrow) * 64 + g * 8];
  qf[1] = *(const short8*)&Qb[(long)(q0 + qrow) * 64 + 32 + g * 8];

  const short8 ones = (short8)(short)0x3F80;  // bf16 1.0 x8
  float4v lacc = (float4v)0.f;
  float4v oacc[4];
#pragma unroll
  for (int di = 0; di < 4; ++di) oacc[di] = (float4v)0.f;

  // prologue: stage it 0 into buf 0
  glds16(Kb + koff, &Ks[0][w * 512]);
  glds16(Vb + voff, &Vs[0][w * 512]);

  for (int it = 0; it < NIT; ++it) {
    const int buf = it & 1;
    if (it + 1 < NIT) {
      // issue it+1 into the other buffer (last read before it-1's end bar)
      glds16(Kb + (long)(it + 1) * 64 * 64 + koff, &Ks[buf ^ 1][w * 512]);
      glds16(Vb + (it + 1) * 64 + voff, &Vs[buf ^ 1][w * 512]);
      __builtin_amdgcn_sched_barrier(0);
      asm volatile("s_waitcnt vmcnt(2)" ::: "memory");  // it's 2 landed
    } else {
      __builtin_amdgcn_sched_barrier(0);
      asm volatile("s_waitcnt vmcnt(0)" ::: "memory");
    }
    sbar();

    // S^T tile: rows = kv (64), cols = q (wave strip of 16)
    float4v sacc[4];
#pragma unroll
    for (int i = 0; i < 4; ++i) sacc[i] = (float4v)0.f;
#pragma unroll
    for (int i = 0; i < 4; ++i) {
      const short8 a0 = *(const short8*)&Ks[buf][ko0 + i * 1024];
      sacc[i] = __builtin_amdgcn_mfma_f32_16x16x32_bf16(a0, qf[0], sacc[i], 0, 0, 0);
    }
#pragma unroll
    for (int i = 0; i < 4; ++i) {
      const short8 a1 = *(const short8*)&Ks[buf][ko1 + i * 1024];
      sacc[i] = __builtin_amdgcn_mfma_f32_16x16x32_bf16(a1, qf[1], sacc[i], 0, 0, 0);
    }

    // fixed-shift softmax: p = exp2(s) (bare v_exp_f32), pack bf16 -> Ps
#pragma unroll
    for (int i = 0; i < 4; ++i) {
      union { float f; unsigned u; } a0, a1, a2, a3;
      a0.f = fexp2(sacc[i][0]);
      a1.f = fexp2(sacc[i][1]);
      a2.f = fexp2(sacc[i][2]);
      a3.f = fexp2(sacc[i][3]);
      const unsigned d0 = __builtin_amdgcn_perm(a1.u + 0x8000u, a0.u + 0x8000u, 0x07060302u);
      const unsigned d1 = __builtin_amdgcn_perm(a3.u + 0x8000u, a2.u + 0x8000u, 0x07060302u);
      *(uint2v*)&Ps[pw[i]] = (uint2v){d0, d1};
    }

    // O^T += V^T * P^T; l += 1^T * P^T (Ps rows wave-private; no barrier)
#pragma unroll
    for (int ks = 0; ks < 2; ++ks) {
      const short8 pf = *(const short8*)&Ps[pr[ks]];
      lacc = __builtin_amdgcn_mfma_f32_16x16x32_bf16(ones, pf, lacc, 0, 0, 0);
#pragma unroll
      for (int di = 0; di < 4; ++di) {
        const short8 vf = *(const short8*)&Vs[buf][vo[ks] + di * 1024];
        oacc[di] = __builtin_amdgcn_mfma_f32_16x16x32_bf16(vf, pf, oacc[di], 0, 0, 0);
      }
    }
    sbar();  // all waves done reading buf before it+2's DMA can touch it
  }

  // all-ones A => every C row/reg of lacc equals l(q=lr)
  const float inv = 1.f / lacc[0];

  const int q = q0 + qrow;
#pragma unroll
  for (int di = 0; di < 4; ++di) {
    short4v o;
#pragma unroll
    for (int t = 0; t < 4; ++t) o[t] = f2bf(oacc[di][t] * inv);
    *(short4v*)&Ctx[(long)(b * S + q) * 2048 + h * 64 + di * 16 + g * 4] = o;
  }
}

// ---------------------------------------------------------------------------
extern "C" void kernel_launch(void* const* d_in, const int* in_sizes, int n_in,
                              void* d_out, int out_size, void* d_ws, size_t ws_size,
                              hipStream_t stream) {
  (void)in_sizes; (void)n_in; (void)out_size; (void)ws_size;
  const float* X    = (const float*)d_in[0];
  const float* cosp = (const float*)d_in[2];
  const float* sinp = (const float*)d_in[3];
  const float* Wq   = (const float*)d_in[4];
  const float* Wk   = (const float*)d_in[5];
  const float* Wv   = (const float*)d_in[6];
  const float* Wo   = (const float*)d_in[7];
  float* out = (float*)d_out;
  char* ws = (char*)d_ws;

  short* Xb = (short*)(ws + 0);           // 16.8 MB bf16 X
  short* WT = (short*)(ws + 16777216);    // 12.6 MB fused QKV^T; reused for Wo^T
  short* Y  = (short*)(ws + 29360128);    // 25.2 MB fused QKV out; reused as Ctx
  short* Qr = (short*)(ws + 54525952);    // 16.8 MB
  short* Kr = (short*)(ws + 71303168);    // 4.2 MB
  short* Vt = (short*)(ws + 75497472);    // 4.2 MB  (total 79.7 MB)

  f32_to_bf16<<<4096, 256, 0, stream>>>(X, Xb);
  // fused QKV^T: rows [0,2048)=Wq^T, [2048,2560)=Wk^T, [2560,3072)=Wv^T
  wtrans3<<<dim3(32, 32, 3), 256, 0, stream>>>(Wq, Wk, Wv, WT);

  // fused QKV projection: Y (4096 x 3072), 256^2 tiles -> 12x16 = 192 blocks
  gemm256<short><<<dim3(12, 16), 512, 0, stream>>>(Xb, WT, Y, 4096, 3072, 2048);

  // Wo^T reuses WT (QKV GEMM already consumed it in stream order)
  transpose_f2b<<<dim3(32, 32), 256, 0, stream>>>(Wo, WT, 2048, 2048);

  // RoPE; Q pre-scaled by log2(e)/sqrt(hd) = log2(e)/8 for exp2-domain softmax
  rope_kernel<<<16384, 256, 0, stream>>>(Y, cosp, sinp, Qr, 32, 5, 3072, 0, 0.18033688011112043f);
  rope_kernel<<<4096, 256, 0, stream>>>(Y, cosp, sinp, Kr, 8, 3, 3072, 2048, 1.0f);
  vtrans<<<dim3(32, 16), 256, 0, stream>>>(Y, Vt, 3072, 2560);

  // attention -> Ctx (aliases Y, already consumed)
  attn_kernel<<<dim3(16, 64), 512, 0, stream>>>(Qr, Kr, Vt, Y);

  // output projection (fp32 out), 8x16 = 128 blocks
  gemm256<float><<<dim3(8, 16), 512, 0, stream>>>(Y, WT, out, 4096, 2048, 2048);
}

// Round 4
// 379.290 us; speedup vs baseline: 1.0187x; 1.0015x over previous
//
#include <hip/hip_runtime.h>
#include <stdint.h>

typedef __attribute__((ext_vector_type(8))) short short8;
typedef __attribute__((ext_vector_type(4))) short short4v;
typedef __attribute__((ext_vector_type(4))) float float4v;
typedef __attribute__((ext_vector_type(2))) unsigned uint2v;

__device__ __forceinline__ float bf2f(short s) {
  union { unsigned u; float f; } x;
  x.u = ((unsigned)(unsigned short)s) << 16;
  return x.f;
}
__device__ __forceinline__ short f2bf(float f) {
  union { float f; unsigned u; } x;
  x.f = f;
  unsigned r = x.u + 0x7fffu + ((x.u >> 16) & 1u);
  return (short)(r >> 16);
}
// bare v_exp_f32 — exp2f() calls __ocml_exp2_f32 (range/denorm fixups, ~30
// VALU); our scores are bounded |s|<~50 so the raw HW op is exact.
__device__ __forceinline__ float fexp2(float x) {
#if __has_builtin(__builtin_amdgcn_exp2f)
  return __builtin_amdgcn_exp2f(x);
#else
  float r;
  asm("v_exp_f32 %0, %1" : "=v"(r) : "v"(x));
  return r;
#endif
}
__device__ __forceinline__ void glds16(const void* g, void* l) {
  __builtin_amdgcn_global_load_lds(
      (const __attribute__((address_space(1))) void*)g,
      (__attribute__((address_space(3))) void*)l, 16, 0, 0);
}
// Plain raw barrier — no sched_barrier(0) pins. s_barrier has unmodeled side
// effects, so memory ops (glds16/ds_read) cannot migrate across it; pinning
// the whole schedule around every barrier was the m141 failure mode (510 TF).
__device__ __forceinline__ void bar() { __builtin_amdgcn_s_barrier(); }

// ---------------------------------------------------------------------------
// fp32 -> bf16 elementwise, 8 elems/thread.
// ---------------------------------------------------------------------------
__global__ __launch_bounds__(256) void f32_to_bf16(const float* __restrict__ s,
                                                   short* __restrict__ d) {
  const long i = ((long)blockIdx.x * 256 + threadIdx.x) * 8;
  const float4v a = *(const float4v*)&s[i];
  const float4v b = *(const float4v*)&s[i + 4];
  short8 v;
#pragma unroll
  for (int e = 0; e < 4; ++e) { v[e] = f2bf(a[e]); v[e + 4] = f2bf(b[e]); }
  *(short8*)&d[i] = v;
}

// ---------------------------------------------------------------------------
// fp32 transpose -> bf16: src (R x C, f32) -> dst (C x R, bf16), 64x64 tiles.
// ---------------------------------------------------------------------------
__device__ __forceinline__ void transpose_tile(
    const float* __restrict__ src, short* __restrict__ dst, int R, int C,
    int r0, int c0) {
  __shared__ short t[64 * 72];
  const int tid = threadIdx.x;
#pragma unroll
  for (int r = 0; r < 2; ++r) {
    int c = r * 256 + tid;
    int row = c >> 3, col8 = (c & 7) * 8;
    const float4v a = *(const float4v*)&src[(long)(r0 + row) * C + c0 + col8];
    const float4v b = *(const float4v*)&src[(long)(r0 + row) * C + c0 + col8 + 4];
    short8 v;
#pragma unroll
    for (int e = 0; e < 4; ++e) { v[e] = f2bf(a[e]); v[e + 4] = f2bf(b[e]); }
    *(short8*)&t[row * 72 + col8] = v;
  }
  __syncthreads();
#pragma unroll
  for (int r = 0; r < 2; ++r) {
    int c = r * 256 + tid;
    int orow = c >> 3, ocol8 = (c & 7) * 8;
    short8 w;
#pragma unroll
    for (int e = 0; e < 8; ++e) w[e] = t[(ocol8 + e) * 72 + orow];
    *(short8*)&dst[(long)(c0 + orow) * R + r0 + ocol8] = w;
  }
}

__global__ __launch_bounds__(256) void transpose_f2b(
    const float* __restrict__ src, short* __restrict__ dst, int R, int C) {
  transpose_tile(src, dst, R, C, blockIdx.y * 64, blockIdx.x * 64);
}

// Fused QKV weight transpose: z=0 Wq (C=2048), z=1 Wk, z=2 Wv (C=512).
__global__ __launch_bounds__(256) void wtrans3(
    const float* __restrict__ Wq, const float* __restrict__ Wk,
    const float* __restrict__ Wv, short* __restrict__ WT) {
  const int z = blockIdx.z;
  const float* src = z == 0 ? Wq : (z == 1 ? Wk : Wv);
  const int C = z == 0 ? 2048 : 512;
  if (blockIdx.x * 64 >= C) return;
  short* dst = WT + (z == 0 ? 0 : (z == 1 ? 2048 * 2048 : 2560 * 2048));
  transpose_tile(src, dst, 2048, C, blockIdx.y * 64, blockIdx.x * 64);
}

// ---------------------------------------------------------------------------
// V reshape+transpose: Y (B,S,ld) cols [col0, col0+512) bf16 -> Vt (B,G,64,S).
// grid: (S/64, B*G)
// ---------------------------------------------------------------------------
__global__ __launch_bounds__(256) void vtrans(const short* __restrict__ Y,
                                              short* __restrict__ Vt,
                                              int ld, int col0) {
  const int bg = blockIdx.y;
  const int b = bg >> 3, gk = bg & 7;
  const int s0 = blockIdx.x * 64;
  __shared__ short t[64 * 72];
  const int tid = threadIdx.x;
#pragma unroll
  for (int r = 0; r < 2; ++r) {
    int c = r * 256 + tid;
    int row = c >> 3, col8 = (c & 7) * 8;
    short8 v = *(const short8*)&Y[(long)(b * 2048 + s0 + row) * ld + col0 + gk * 64 + col8];
    *(short8*)&t[row * 72 + col8] = v;
  }
  __syncthreads();
#pragma unroll
  for (int r = 0; r < 2; ++r) {
    int c = r * 256 + tid;
    int d = c >> 3, s8 = (c & 7) * 8;
    short8 w;
#pragma unroll
    for (int e = 0; e < 8; ++e) w[e] = t[(s8 + e) * 72 + d];
    *(short8*)&Vt[((long)bg * 64 + d) * 2048 + s0 + s8] = w;
  }
}

// ---------------------------------------------------------------------------
// RoPE + layout change: Y (B,S,ld) cols [col0, col0+NH*64) -> out (B,NH,S,64).
// ---------------------------------------------------------------------------
__global__ __launch_bounds__(256) void rope_kernel(
    const short* __restrict__ Y, const float* __restrict__ cosp,
    const float* __restrict__ sinp, short* __restrict__ out,
    int NH, int lgNH, int ld, int col0, float scale) {
  const long tid = (long)blockIdx.x * 256 + threadIdx.x;
  const int d = (int)(tid & 31);
  const long t1 = tid >> 5;
  const int h = (int)(t1 & (NH - 1));
  const long t2 = t1 >> lgNH;
  const int s = (int)(t2 & 2047);
  const int b = (int)(t2 >> 11);
  const long ib = (long)(b * 2048 + s) * ld + col0 + h * 64 + d;
  const float x1 = bf2f(Y[ib]);
  const float x2 = bf2f(Y[ib + 32]);
  const float c1 = cosp[s * 64 + d];
  const float c2 = cosp[s * 64 + d + 32];
  const float s1 = sinp[s * 64 + d];
  const float s2 = sinp[s * 64 + d + 32];
  const long ob = ((long)(b * NH + h) * 2048 + s) * 64 + d;
  out[ob] = f2bf((x1 * c1 - x2 * s1) * scale);
  out[ob + 32] = f2bf((x2 * c2 + x1 * s2) * scale);
}

// ---------------------------------------------------------------------------
// GEMM, 256x256 tile, BK=64, 8 waves (2M x 4N), phase schedule with counted
// vmcnt. C (MxN) = A (MxK,bf16) * BT (NxK,bf16)^T.
// - 2-bit LDS swizzle: col ^= ((row>>2)&1)<<4 ^ ((row>>3)&1)<<5 — each b128
//   fragment read spreads 8 lanes per 16-B quad over all 32 banks (verified
//   conflict-free minimum). Pre-swizzled global SOURCE + swizzled ds_read.
// - XCD-aware chunked block remap (nwg % 8 == 0 at both call sites).
// - 4 phases/K-tile, prefetch t+2 into the buffer being read; each region
//   staged only after the barrier that follows its last reader. Boundary
//   s_waitcnt vmcnt(8) retires exactly tile t+1's loads.
// - Plain s_barrier (NO sched_barrier pins — m141: full pins = 510 TF).
// ---------------------------------------------------------------------------
template <typename OutT>
__global__ __launch_bounds__(512, 2) void gemm256(
    const short* __restrict__ A, const short* __restrict__ BT,
    OutT* __restrict__ C, int M, int N, int K) {
  (void)M;
  __shared__ short As[2][16384];  // [buf][256 rows x 64 cols]
  __shared__ short Bs[2][16384];
  const int tid = threadIdx.x;
  const int w = tid >> 6, lane = tid & 63;
  const int g = lane >> 4, lr = lane & 15;
  const int wm = w >> 2, wn = w & 3;

  // XCD-aware chunked bijective remap (requires nwg % 8 == 0)
  const int nbx = gridDim.x;
  const int nwg = nbx * gridDim.y;
  const int bid = blockIdx.y * nbx + blockIdx.x;
  const int cpx = nwg >> 3;
  const int nbid = (bid & 7) * cpx + (bid >> 3);
  const int m0 = (nbid / nbx) << 8, n0 = (nbid % nbx) << 8;

  // staging: thread row r0 = tid>>3, col8 = (tid&7)*8; source col carries the
  // inverse (= same, involution) swizzle keyed on row bits 2,3.
  const int r0 = tid >> 3;
  const int scol = ((tid & 7) << 3) ^ (((r0 >> 2) & 1) << 4) ^ (((r0 >> 3) & 1) << 5);
  const long aoff = (long)(m0 + r0) * K + scol;
  const long boff = (long)(n0 + r0) * K + scol;

  // ds_read offsets (element units); row bits 2,3 within a 16-row MFMA block
  // are lr bits 2,3.
  const int swz = (((lr >> 2) & 1) << 4) | (((lr >> 3) & 1) << 5);
  const int acol0 = (g << 3) ^ swz;         // kk = 0
  const int acol1 = (32 + (g << 3)) ^ swz;  // kk = 1
  const int abase = (wm * 128 + lr) * 64;
  const int bbase = (wn * 64 + lr) * 64;

  float4v acc[8][4];
#pragma unroll
  for (int i = 0; i < 8; ++i)
#pragma unroll
    for (int j = 0; j < 4; ++j) acc[i][j] = (float4v)0.f;

#define STAGE_A(l, buf, kg)                                          \
  glds16(A + aoff + (long)(l) * 64 * K + (kg),                       \
         &As[(buf)][(l) * 4096 + w * 512])
#define STAGE_B(l, buf, kg)                                          \
  glds16(BT + boff + (long)(l) * 64 * K + (kg),                      \
         &Bs[(buf)][(l) * 4096 + w * 512])

  const int NT = K >> 6;
  // prologue: tile 0 -> buf0 (8 loads), tile 1 -> buf1 (8 loads)
#pragma unroll
  for (int l = 0; l < 4; ++l) { STAGE_A(l, 0, 0); STAGE_B(l, 0, 0); }
#pragma unroll
  for (int l = 0; l < 4; ++l) { STAGE_A(l, 1, 64); STAGE_B(l, 1, 64); }
  asm volatile("s_waitcnt vmcnt(8)" ::: "memory");  // tile 0 landed
  __builtin_amdgcn_sched_barrier(0);
  bar();

  short8 aR[4][2], bR0[2][2], bR1[2][2];

#define LDA(MH, ASB)                                                       \
  _Pragma("unroll") for (int i = 0; i < 4; ++i) {                          \
    aR[i][0] = *(const short8*)&ASB[abase + ((MH)*4 + i) * 1024 + acol0];  \
    aR[i][1] = *(const short8*)&ASB[abase + ((MH)*4 + i) * 1024 + acol1];  \
  }
#define LDB(NH, BSB, BR)                                                   \
  _Pragma("unroll") for (int j = 0; j < 2; ++j) {                          \
    BR[j][0] = *(const short8*)&BSB[bbase + ((NH)*2 + j) * 1024 + acol0];  \
    BR[j][1] = *(const short8*)&BSB[bbase + ((NH)*2 + j) * 1024 + acol1];  \
  }
#define MMA_Q(MH, NH, BR)                                                  \
  __builtin_amdgcn_s_setprio(1);                                           \
  _Pragma("unroll") for (int kk = 0; kk < 2; ++kk)                         \
  _Pragma("unroll") for (int i = 0; i < 4; ++i)                            \
  _Pragma("unroll") for (int j = 0; j < 2; ++j)                            \
    acc[(MH)*4 + i][(NH)*2 + j] = __builtin_amdgcn_mfma_f32_16x16x32_bf16( \
        aR[i][kk], BR[j][kk], acc[(MH)*4 + i][(NH)*2 + j], 0, 0, 0);       \
  __builtin_amdgcn_s_setprio(0);

  for (int t = 0; t < NT; ++t) {
    const short* const Asb = As[t & 1];
    const short* const Bsb = Bs[t & 1];
    const long kg = (long)(t + 2) << 6;
    const bool pre = (t + 2) < NT;

    // phase 0: quadrant (0,0)
    LDA(0, Asb);
    LDB(0, Bsb, bR0);
    bar();
    MMA_Q(0, 0, bR0);
    bar();
    // phase 1: (0,1); prefetch A halves 0,2 of t+2 (rows consumed in ph0)
    LDB(1, Bsb, bR1);
    if (pre) { STAGE_A(0, t & 1, kg); STAGE_A(2, t & 1, kg); }
    bar();
    MMA_Q(0, 1, bR1);
    bar();
    // phase 2: (1,1); prefetch all B of t+2 (B fully consumed after ph1)
    LDA(1, Asb);
    if (pre) {
      STAGE_B(0, t & 1, kg); STAGE_B(1, t & 1, kg);
      STAGE_B(2, t & 1, kg); STAGE_B(3, t & 1, kg);
    }
    bar();
    MMA_Q(1, 1, bR1);
    bar();
    // phase 3: (1,0); prefetch A halves 1,3 (rows consumed in ph2)
    if (pre) { STAGE_A(1, t & 1, kg); STAGE_A(3, t & 1, kg); }
    bar();
    MMA_Q(1, 0, bR0);
    // boundary: counted drain — keep this tile's 8 prefetch loads in flight
    if (pre) { asm volatile("s_waitcnt vmcnt(8)" ::: "memory"); }
    else     { asm volatile("s_waitcnt vmcnt(0)" ::: "memory"); }
    __builtin_amdgcn_sched_barrier(0);
    bar();
  }

#pragma unroll
  for (int i = 0; i < 8; ++i)
#pragma unroll
    for (int j = 0; j < 4; ++j)
#pragma unroll
      for (int t4 = 0; t4 < 4; ++t4) {
        const int r = m0 + wm * 128 + i * 16 + g * 4 + t4;
        const int cc = n0 + wn * 64 + j * 16 + lr;
        const float v = acc[i][j][t4];
        if constexpr (sizeof(OutT) == 2)
          C[(long)r * N + cc] = f2bf(v);
        else
          C[(long)r * N + cc] = v;
      }
#undef STAGE_A
#undef STAGE_B
#undef LDA
#undef LDB
#undef MMA_Q
}

// ---------------------------------------------------------------------------
// Flash attention, transposed formulation, fixed-shift softmax.
// Qr (B,H,S,64) pre-scaled by log2(e)/8, Kr (B,G,S,64), Vt (B,G,64,S).
// Block: 512 thr (8 waves), 128 q x full S. S^T = K*Q^T, O^T = V^T*P^T.
// KVBLK=64, 32 iterations, double-buffered K/V staging (raw barriers +
// counted vmcnt(2)). LDS 48 KiB -> 3 blocks/CU. setprio around MFMA
// clusters (T5, m191 +4-7% attn). Plain s_barrier (no sched pins).
// ---------------------------------------------------------------------------
__global__ __launch_bounds__(512, 6) void attn_kernel(
    const short* __restrict__ Qr, const short* __restrict__ Kr,
    const short* __restrict__ Vt, short* __restrict__ Ctx) {
  constexpr int S = 2048;
  constexpr int NIT = 32;
  const int bh = blockIdx.y;
  const int b = bh >> 5, h = bh & 31;
  const int gk = h >> 2;
  const int q0 = blockIdx.x << 7;
  const int tid = threadIdx.x;
  const int w = tid >> 6, lane = tid & 63;
  const int g = lane >> 4, lr = lane & 15;
  const int b8 = lr & 7;
  const int qrow = w * 16 + lr;

  __shared__ short Ks[2][64 * 64];  // [buf][kv][d], granule swizzle by kv&7
  __shared__ short Vs[2][64 * 64];  // [buf][d][kv], granule swizzle by d&7
  __shared__ short Ps[128 * 64];    // [q][kv],      granule swizzle by q&7

  const short* Qb = Qr + (long)(b * 32 + h) * S * 64;
  const short* Kb = Kr + (long)(b * 8 + gk) * S * 64;
  const short* Vb = Vt + (long)(b * 8 + gk) * 64 * S;

  // LDS read element-offsets
  const int ko0 = lr * 64 + ((0 + g) ^ b8) * 8;  // Ks, kk=0; +i*1024, i<4
  const int ko1 = lr * 64 + ((4 + g) ^ b8) * 8;  // Ks, kk=1
  int vo[2], pr[2], pw[4];
#pragma unroll
  for (int ks = 0; ks < 2; ++ks) {
    vo[ks] = lr * 64 + ((ks * 4 + g) ^ b8) * 8;    // Vs; +di*1024
    pr[ks] = qrow * 64 + ((ks * 4 + g) ^ b8) * 8;  // Ps read
  }
#pragma unroll
  for (int i = 0; i < 4; ++i)
    pw[i] = qrow * 64 + ((2 * i + (g >> 1)) ^ b8) * 8 + (g & 1) * 4;

  // staging: one glds16 each for K and V per iteration (8 KB each).
  // thread covers LDS row tid>>3, granule tid&7; global col pre-swizzled.
  const int srow = tid >> 3, sl = tid & 7;
  const long koff = (long)srow * 64 + (sl ^ (srow & 7)) * 8;
  const long voff = (long)srow * S + (sl ^ (srow & 7)) * 8;

  short8 qf[2];
  qf[0] = *(const short8*)&Qb[(long)(q0 + qrow) * 64 + g * 8];
  qf[1] = *(const short8*)&Qb[(long)(q0 + qrow) * 64 + 32 + g * 8];

  const short8 ones = (short8)(short)0x3F80;  // bf16 1.0 x8
  float4v lacc = (float4v)0.f;
  float4v oacc[4];
#pragma unroll
  for (int di = 0; di < 4; ++di) oacc[di] = (float4v)0.f;

  // prologue: stage it 0 into buf 0
  glds16(Kb + koff, &Ks[0][w * 512]);
  glds16(Vb + voff, &Vs[0][w * 512]);

  for (int it = 0; it < NIT; ++it) {
    const int buf = it & 1;
    if (it + 1 < NIT) {
      // issue it+1 into the other buffer (last read before it-1's end bar)
      glds16(Kb + (long)(it + 1) * 64 * 64 + koff, &Ks[buf ^ 1][w * 512]);
      glds16(Vb + (it + 1) * 64 + voff, &Vs[buf ^ 1][w * 512]);
      asm volatile("s_waitcnt vmcnt(2)" ::: "memory");  // it's 2 landed
    } else {
      asm volatile("s_waitcnt vmcnt(0)" ::: "memory");
    }
    __builtin_amdgcn_sched_barrier(0);
    bar();

    // S^T tile: rows = kv (64), cols = q (wave strip of 16)
    float4v sacc[4];
#pragma unroll
    for (int i = 0; i < 4; ++i) sacc[i] = (float4v)0.f;
    __builtin_amdgcn_s_setprio(1);
#pragma unroll
    for (int i = 0; i < 4; ++i) {
      const short8 a0 = *(const short8*)&Ks[buf][ko0 + i * 1024];
      sacc[i] = __builtin_amdgcn_mfma_f32_16x16x32_bf16(a0, qf[0], sacc[i], 0, 0, 0);
    }
#pragma unroll
    for (int i = 0; i < 4; ++i) {
      const short8 a1 = *(const short8*)&Ks[buf][ko1 + i * 1024];
      sacc[i] = __builtin_amdgcn_mfma_f32_16x16x32_bf16(a1, qf[1], sacc[i], 0, 0, 0);
    }
    __builtin_amdgcn_s_setprio(0);

    // fixed-shift softmax: p = exp2(s) (bare v_exp_f32), pack bf16 -> Ps
#pragma unroll
    for (int i = 0; i < 4; ++i) {
      union { float f; unsigned u; } a0, a1, a2, a3;
      a0.f = fexp2(sacc[i][0]);
      a1.f = fexp2(sacc[i][1]);
      a2.f = fexp2(sacc[i][2]);
      a3.f = fexp2(sacc[i][3]);
      const unsigned d0 = __builtin_amdgcn_perm(a1.u + 0x8000u, a0.u + 0x8000u, 0x07060302u);
      const unsigned d1 = __builtin_amdgcn_perm(a3.u + 0x8000u, a2.u + 0x8000u, 0x07060302u);
      *(uint2v*)&Ps[pw[i]] = (uint2v){d0, d1};
    }

    // O^T += V^T * P^T; l += 1^T * P^T (Ps rows wave-private; no barrier)
    __builtin_amdgcn_s_setprio(1);
#pragma unroll
    for (int ks = 0; ks < 2; ++ks) {
      const short8 pf = *(const short8*)&Ps[pr[ks]];
      lacc = __builtin_amdgcn_mfma_f32_16x16x32_bf16(ones, pf, lacc, 0, 0, 0);
#pragma unroll
      for (int di = 0; di < 4; ++di) {
        const short8 vf = *(const short8*)&Vs[buf][vo[ks] + di * 1024];
        oacc[di] = __builtin_amdgcn_mfma_f32_16x16x32_bf16(vf, pf, oacc[di], 0, 0, 0);
      }
    }
    __builtin_amdgcn_s_setprio(0);
    bar();  // all waves done reading buf before it+2's DMA can touch it
  }

  // all-ones A => every C row/reg of lacc equals l(q=lr)
  const float inv = 1.f / lacc[0];

  const int q = q0 + qrow;
#pragma unroll
  for (int di = 0; di < 4; ++di) {
    short4v o;
#pragma unroll
    for (int t = 0; t < 4; ++t) o[t] = f2bf(oacc[di][t] * inv);
    *(short4v*)&Ctx[(long)(b * S + q) * 2048 + h * 64 + di * 16 + g * 4] = o;
  }
}

// ---------------------------------------------------------------------------
extern "C" void kernel_launch(void* const* d_in, const int* in_sizes, int n_in,
                              void* d_out, int out_size, void* d_ws, size_t ws_size,
                              hipStream_t stream) {
  (void)in_sizes; (void)n_in; (void)out_size; (void)ws_size;
  const float* X    = (const float*)d_in[0];
  const float* cosp = (const float*)d_in[2];
  const float* sinp = (const float*)d_in[3];
  const float* Wq   = (const float*)d_in[4];
  const float* Wk   = (const float*)d_in[5];
  const float* Wv   = (const float*)d_in[6];
  const float* Wo   = (const float*)d_in[7];
  float* out = (float*)d_out;
  char* ws = (char*)d_ws;

  short* Xb = (short*)(ws + 0);           // 16.8 MB bf16 X
  short* WT = (short*)(ws + 16777216);    // 12.6 MB fused QKV^T; reused for Wo^T
  short* Y  = (short*)(ws + 29360128);    // 25.2 MB fused QKV out; reused as Ctx
  short* Qr = (short*)(ws + 54525952);    // 16.8 MB
  short* Kr = (short*)(ws + 71303168);    // 4.2 MB
  short* Vt = (short*)(ws + 75497472);    // 4.2 MB  (total 79.7 MB)

  f32_to_bf16<<<4096, 256, 0, stream>>>(X, Xb);
  // fused QKV^T: rows [0,2048)=Wq^T, [2048,2560)=Wk^T, [2560,3072)=Wv^T
  wtrans3<<<dim3(32, 32, 3), 256, 0, stream>>>(Wq, Wk, Wv, WT);

  // fused QKV projection: Y (4096 x 3072), 256^2 tiles -> 12x16 = 192 blocks
  gemm256<short><<<dim3(12, 16), 512, 0, stream>>>(Xb, WT, Y, 4096, 3072, 2048);

  // Wo^T reuses WT (QKV GEMM already consumed it in stream order)
  transpose_f2b<<<dim3(32, 32), 256, 0, stream>>>(Wo, WT, 2048, 2048);

  // RoPE; Q pre-scaled by log2(e)/sqrt(hd) = log2(e)/8 for exp2-domain softmax
  rope_kernel<<<16384, 256, 0, stream>>>(Y, cosp, sinp, Qr, 32, 5, 3072, 0, 0.18033688011112043f);
  rope_kernel<<<4096, 256, 0, stream>>>(Y, cosp, sinp, Kr, 8, 3, 3072, 2048, 1.0f);
  vtrans<<<dim3(32, 16), 256, 0, stream>>>(Y, Vt, 3072, 2560);

  // attention -> Ctx (aliases Y, already consumed)
  attn_kernel<<<dim3(16, 64), 512, 0, stream>>>(Qr, Kr, Vt, Y);

  // output projection (fp32 out), 8x16 = 128 blocks
  gemm256<float><<<dim3(8, 16), 512, 0, stream>>>(Y, WT, out, 4096, 2048, 2048);
}

// Round 5
// 370.398 us; speedup vs baseline: 1.0432x; 1.0240x over previous
//
#include <hip/hip_runtime.h>
#include <stdint.h>

typedef __attribute__((ext_vector_type(8))) short short8;
typedef __attribute__((ext_vector_type(4))) short short4v;
typedef __attribute__((ext_vector_type(4))) float float4v;
typedef __attribute__((ext_vector_type(2))) unsigned uint2v;

__device__ __forceinline__ float bf2f(short s) {
  union { unsigned u; float f; } x;
  x.u = ((unsigned)(unsigned short)s) << 16;
  return x.f;
}
__device__ __forceinline__ short f2bf(float f) {
  union { float f; unsigned u; } x;
  x.f = f;
  unsigned r = x.u + 0x7fffu + ((x.u >> 16) & 1u);
  return (short)(r >> 16);
}
// bare v_exp_f32 — exp2f() calls __ocml_exp2_f32 (range/denorm fixups, ~30
// VALU); our scores are bounded |s|<~50 so the raw HW op is exact.
__device__ __forceinline__ float fexp2(float x) {
#if __has_builtin(__builtin_amdgcn_exp2f)
  return __builtin_amdgcn_exp2f(x);
#else
  float r;
  asm("v_exp_f32 %0, %1" : "=v"(r) : "v"(x));
  return r;
#endif
}
__device__ __forceinline__ void glds16(const void* g, void* l) {
  __builtin_amdgcn_global_load_lds(
      (const __attribute__((address_space(1))) void*)g,
      (__attribute__((address_space(3))) void*)l, 16, 0, 0);
}
__device__ __forceinline__ void bar() { __builtin_amdgcn_s_barrier(); }

// ---------------------------------------------------------------------------
// fp32 -> bf16 elementwise, 8 elems/thread.
// ---------------------------------------------------------------------------
__global__ __launch_bounds__(256) void f32_to_bf16(const float* __restrict__ s,
                                                   short* __restrict__ d) {
  const long i = ((long)blockIdx.x * 256 + threadIdx.x) * 8;
  const float4v a = *(const float4v*)&s[i];
  const float4v b = *(const float4v*)&s[i + 4];
  short8 v;
#pragma unroll
  for (int e = 0; e < 4; ++e) { v[e] = f2bf(a[e]); v[e + 4] = f2bf(b[e]); }
  *(short8*)&d[i] = v;
}

// ---------------------------------------------------------------------------
// fp32 transpose -> bf16: src (R x C, f32) -> dst (C x R, bf16), 64x64 tiles.
// ---------------------------------------------------------------------------
__device__ __forceinline__ void transpose_tile(
    const float* __restrict__ src, short* __restrict__ dst, int R, int C,
    int r0, int c0) {
  __shared__ short t[64 * 72];
  const int tid = threadIdx.x;
#pragma unroll
  for (int r = 0; r < 2; ++r) {
    int c = r * 256 + tid;
    int row = c >> 3, col8 = (c & 7) * 8;
    const float4v a = *(const float4v*)&src[(long)(r0 + row) * C + c0 + col8];
    const float4v b = *(const float4v*)&src[(long)(r0 + row) * C + c0 + col8 + 4];
    short8 v;
#pragma unroll
    for (int e = 0; e < 4; ++e) { v[e] = f2bf(a[e]); v[e + 4] = f2bf(b[e]); }
    *(short8*)&t[row * 72 + col8] = v;
  }
  __syncthreads();
#pragma unroll
  for (int r = 0; r < 2; ++r) {
    int c = r * 256 + tid;
    int orow = c >> 3, ocol8 = (c & 7) * 8;
    short8 w;
#pragma unroll
    for (int e = 0; e < 8; ++e) w[e] = t[(ocol8 + e) * 72 + orow];
    *(short8*)&dst[(long)(c0 + orow) * R + r0 + ocol8] = w;
  }
}

__global__ __launch_bounds__(256) void transpose_f2b(
    const float* __restrict__ src, short* __restrict__ dst, int R, int C) {
  transpose_tile(src, dst, R, C, blockIdx.y * 64, blockIdx.x * 64);
}

// Fused QKV weight transpose: z=0 Wq (C=2048), z=1 Wk, z=2 Wv (C=512).
__global__ __launch_bounds__(256) void wtrans3(
    const float* __restrict__ Wq, const float* __restrict__ Wk,
    const float* __restrict__ Wv, short* __restrict__ WT) {
  const int z = blockIdx.z;
  const float* src = z == 0 ? Wq : (z == 1 ? Wk : Wv);
  const int C = z == 0 ? 2048 : 512;
  if (blockIdx.x * 64 >= C) return;
  short* dst = WT + (z == 0 ? 0 : (z == 1 ? 2048 * 2048 : 2560 * 2048));
  transpose_tile(src, dst, 2048, C, blockIdx.y * 64, blockIdx.x * 64);
}

// ---------------------------------------------------------------------------
// V reshape+transpose: YV (B,S,ld) cols [col0, col0+512) bf16 -> Vt (B,G,64,S).
// grid: (S/64, B*G)
// ---------------------------------------------------------------------------
__global__ __launch_bounds__(256) void vtrans(const short* __restrict__ Y,
                                              short* __restrict__ Vt,
                                              int ld, int col0) {
  const int bg = blockIdx.y;
  const int b = bg >> 3, gk = bg & 7;
  const int s0 = blockIdx.x * 64;
  __shared__ short t[64 * 72];
  const int tid = threadIdx.x;
#pragma unroll
  for (int r = 0; r < 2; ++r) {
    int c = r * 256 + tid;
    int row = c >> 3, col8 = (c & 7) * 8;
    short8 v = *(const short8*)&Y[(long)(b * 2048 + s0 + row) * ld + col0 + gk * 64 + col8];
    *(short8*)&t[row * 72 + col8] = v;
  }
  __syncthreads();
#pragma unroll
  for (int r = 0; r < 2; ++r) {
    int c = r * 256 + tid;
    int d = c >> 3, s8 = (c & 7) * 8;
    short8 w;
#pragma unroll
    for (int e = 0; e < 8; ++e) w[e] = t[(s8 + e) * 72 + d];
    *(short8*)&Vt[((long)bg * 64 + d) * 2048 + s0 + s8] = w;
  }
}

// ---------------------------------------------------------------------------
// GEMM: C (MxN) = A (MxK,bf16) * BT (NxK,bf16)^T. 128x128 tile, 4 waves.
// (r0-proven m97-class structure; only additions: XCD chunked remap and the
// MODE=1 fused RoPE/layout epilogue.)
// MODE 1: QKV projection epilogue — each wave's 64-col strip is one head.
//   h<32: RoPE+scale -> Qr (B,32,S,64); h in [32,40): RoPE -> Kr (B,8,S,64);
//   h>=40: plain bf16 -> YV (B,S,512). Rope pair (d, d+32) = acc[i][j] and
//   acc[i][j+2], in-thread; computed on f32 acc (closer to ref than the old
//   bf16-roundtrip rope_kernel).
// MODE 2: plain f32 store to Cf.
// ---------------------------------------------------------------------------
template <int MODE>
__global__ __launch_bounds__(256) void gemm_bt(
    const short* __restrict__ A, const short* __restrict__ BT,
    float* __restrict__ Cf, short* __restrict__ Qr, short* __restrict__ Kr,
    short* __restrict__ YV, const float* __restrict__ cosp,
    const float* __restrict__ sinp, int M, int N, int K) {
  (void)M;
  __shared__ short As[128 * 32];
  __shared__ short Bs[128 * 32];
  const int tid = threadIdx.x;
  const int wave = tid >> 6, lane = tid & 63;
  const int g = lane >> 4, lr = lane & 15;
  const int wr = wave >> 1, wc = wave & 1;

  // XCD-aware chunked bijective remap (nwg % 8 == 0 at both call sites)
  const int nbx = gridDim.x;
  const int nwg = nbx * gridDim.y;
  const int bid = blockIdx.y * nbx + blockIdx.x;
  const int nbid = (bid & 7) * (nwg >> 3) + (bid >> 3);
  const int m0 = (nbid / nbx) << 7, n0 = (nbid % nbx) << 7;

  float4v acc[4][4];
#pragma unroll
  for (int i = 0; i < 4; ++i)
#pragma unroll
    for (int j = 0; j < 4; ++j) acc[i][j] = (float4v)0.f;

  for (int kt = 0; kt < K; kt += 32) {
#pragma unroll
    for (int r = 0; r < 2; ++r) {
      const int cb = r * 256 + wave * 64;
      const int c = cb + lane;
      const int row = c >> 2, kc = c & 3;
      glds16(A + (long)(m0 + row) * K + kt + kc * 8, As + cb * 8);
      glds16(BT + (long)(n0 + row) * K + kt + kc * 8, Bs + cb * 8);
    }
    __syncthreads();
    short8 af[4], bfr[4];
#pragma unroll
    for (int i = 0; i < 4; ++i)
      af[i] = *(const short8*)&As[(wr * 64 + i * 16 + lr) * 32 + g * 8];
#pragma unroll
    for (int j = 0; j < 4; ++j)
      bfr[j] = *(const short8*)&Bs[(wc * 64 + j * 16 + lr) * 32 + g * 8];
#pragma unroll
    for (int i = 0; i < 4; ++i)
#pragma unroll
      for (int j = 0; j < 4; ++j)
        acc[i][j] = __builtin_amdgcn_mfma_f32_16x16x32_bf16(af[i], bfr[j], acc[i][j], 0, 0, 0);
    __syncthreads();
  }

  if constexpr (MODE == 1) {
    const int h = (n0 + wc * 64) >> 6;  // head index in [0,48)
#pragma unroll
    for (int i = 0; i < 4; ++i)
#pragma unroll
      for (int t = 0; t < 4; ++t) {
        const int r = m0 + wr * 64 + i * 16 + g * 4 + t;
        const int s = r & 2047, bb = r >> 11;
        if (h < 40) {
          const float sc = h < 32 ? 0.18033688011112043f : 1.0f;
          short* base = h < 32
              ? Qr + ((long)(bb * 32 + h) * 2048 + s) * 64
              : Kr + ((long)(bb * 8 + (h - 32)) * 2048 + s) * 64;
          const float* cr = cosp + s * 64;
          const float* sr = sinp + s * 64;
#pragma unroll
          for (int j = 0; j < 2; ++j) {
            const int d = j * 16 + lr;
            const float x1 = acc[i][j][t];
            const float x2 = acc[i][j + 2][t];
            base[d] = f2bf((x1 * cr[d] - x2 * sr[d]) * sc);
            base[d + 32] = f2bf((x2 * cr[d + 32] + x1 * sr[d + 32]) * sc);
          }
        } else {
          short* base = YV + ((long)bb * 2048 + s) * 512 + (h - 40) * 64;
#pragma unroll
          for (int j = 0; j < 4; ++j) base[j * 16 + lr] = f2bf(acc[i][j][t]);
        }
      }
  } else {
#pragma unroll
    for (int i = 0; i < 4; ++i)
#pragma unroll
      for (int j = 0; j < 4; ++j)
#pragma unroll
        for (int t = 0; t < 4; ++t) {
          const int r = m0 + wr * 64 + i * 16 + g * 4 + t;
          const int cc = n0 + wc * 64 + j * 16 + lr;
          Cf[(long)r * N + cc] = acc[i][j][t];
        }
  }
}

// ---------------------------------------------------------------------------
// Flash attention, transposed formulation, fixed-shift softmax.
// Qr (B,H,S,64) pre-scaled by log2(e)/8, Kr (B,G,S,64), Vt (B,G,64,S).
// Block: 512 thr (8 waves), 128 q x full S. S^T = K*Q^T, O^T = V^T*P^T.
// KVBLK=64, 32 iterations, double-buffered K/V staging (raw barriers +
// counted vmcnt(2)). LDS 48 KiB -> 3 blocks/CU. setprio around MFMA
// clusters (T5). Unchanged from round 4 (97.5 µs measured).
// ---------------------------------------------------------------------------
__global__ __launch_bounds__(512, 6) void attn_kernel(
    const short* __restrict__ Qr, const short* __restrict__ Kr,
    const short* __restrict__ Vt, short* __restrict__ Ctx) {
  constexpr int S = 2048;
  constexpr int NIT = 32;
  const int bh = blockIdx.y;
  const int b = bh >> 5, h = bh & 31;
  const int gk = h >> 2;
  const int q0 = blockIdx.x << 7;
  const int tid = threadIdx.x;
  const int w = tid >> 6, lane = tid & 63;
  const int g = lane >> 4, lr = lane & 15;
  const int b8 = lr & 7;
  const int qrow = w * 16 + lr;

  __shared__ short Ks[2][64 * 64];  // [buf][kv][d], granule swizzle by kv&7
  __shared__ short Vs[2][64 * 64];  // [buf][d][kv], granule swizzle by d&7
  __shared__ short Ps[128 * 64];    // [q][kv],      granule swizzle by q&7

  const short* Qb = Qr + (long)(b * 32 + h) * S * 64;
  const short* Kb = Kr + (long)(b * 8 + gk) * S * 64;
  const short* Vb = Vt + (long)(b * 8 + gk) * 64 * S;

  // LDS read element-offsets
  const int ko0 = lr * 64 + ((0 + g) ^ b8) * 8;  // Ks, kk=0; +i*1024, i<4
  const int ko1 = lr * 64 + ((4 + g) ^ b8) * 8;  // Ks, kk=1
  int vo[2], pr[2], pw[4];
#pragma unroll
  for (int ks = 0; ks < 2; ++ks) {
    vo[ks] = lr * 64 + ((ks * 4 + g) ^ b8) * 8;    // Vs; +di*1024
    pr[ks] = qrow * 64 + ((ks * 4 + g) ^ b8) * 8;  // Ps read
  }
#pragma unroll
  for (int i = 0; i < 4; ++i)
    pw[i] = qrow * 64 + ((2 * i + (g >> 1)) ^ b8) * 8 + (g & 1) * 4;

  // staging: one glds16 each for K and V per iteration (8 KB each).
  const int srow = tid >> 3, sl = tid & 7;
  const long koff = (long)srow * 64 + (sl ^ (srow & 7)) * 8;
  const long voff = (long)srow * S + (sl ^ (srow & 7)) * 8;

  short8 qf[2];
  qf[0] = *(const short8*)&Qb[(long)(q0 + qrow) * 64 + g * 8];
  qf[1] = *(const short8*)&Qb[(long)(q0 + qrow) * 64 + 32 + g * 8];

  const short8 ones = (short8)(short)0x3F80;  // bf16 1.0 x8
  float4v lacc = (float4v)0.f;
  float4v oacc[4];
#pragma unroll
  for (int di = 0; di < 4; ++di) oacc[di] = (float4v)0.f;

  // prologue: stage it 0 into buf 0
  glds16(Kb + koff, &Ks[0][w * 512]);
  glds16(Vb + voff, &Vs[0][w * 512]);

  for (int it = 0; it < NIT; ++it) {
    const int buf = it & 1;
    if (it + 1 < NIT) {
      glds16(Kb + (long)(it + 1) * 64 * 64 + koff, &Ks[buf ^ 1][w * 512]);
      glds16(Vb + (it + 1) * 64 + voff, &Vs[buf ^ 1][w * 512]);
      asm volatile("s_waitcnt vmcnt(2)" ::: "memory");  // it's 2 landed
    } else {
      asm volatile("s_waitcnt vmcnt(0)" ::: "memory");
    }
    __builtin_amdgcn_sched_barrier(0);
    bar();

    // S^T tile: rows = kv (64), cols = q (wave strip of 16)
    float4v sacc[4];
#pragma unroll
    for (int i = 0; i < 4; ++i) sacc[i] = (float4v)0.f;
    __builtin_amdgcn_s_setprio(1);
#pragma unroll
    for (int i = 0; i < 4; ++i) {
      const short8 a0 = *(const short8*)&Ks[buf][ko0 + i * 1024];
      sacc[i] = __builtin_amdgcn_mfma_f32_16x16x32_bf16(a0, qf[0], sacc[i], 0, 0, 0);
    }
#pragma unroll
    for (int i = 0; i < 4; ++i) {
      const short8 a1 = *(const short8*)&Ks[buf][ko1 + i * 1024];
      sacc[i] = __builtin_amdgcn_mfma_f32_16x16x32_bf16(a1, qf[1], sacc[i], 0, 0, 0);
    }
    __builtin_amdgcn_s_setprio(0);

    // fixed-shift softmax: p = exp2(s) (bare v_exp_f32), pack bf16 -> Ps
#pragma unroll
    for (int i = 0; i < 4; ++i) {
      union { float f; unsigned u; } a0, a1, a2, a3;
      a0.f = fexp2(sacc[i][0]);
      a1.f = fexp2(sacc[i][1]);
      a2.f = fexp2(sacc[i][2]);
      a3.f = fexp2(sacc[i][3]);
      const unsigned d0 = __builtin_amdgcn_perm(a1.u + 0x8000u, a0.u + 0x8000u, 0x07060302u);
      const unsigned d1 = __builtin_amdgcn_perm(a3.u + 0x8000u, a2.u + 0x8000u, 0x07060302u);
      *(uint2v*)&Ps[pw[i]] = (uint2v){d0, d1};
    }

    // O^T += V^T * P^T; l += 1^T * P^T (Ps rows wave-private; no barrier)
    __builtin_amdgcn_s_setprio(1);
#pragma unroll
    for (int ks = 0; ks < 2; ++ks) {
      const short8 pf = *(const short8*)&Ps[pr[ks]];
      lacc = __builtin_amdgcn_mfma_f32_16x16x32_bf16(ones, pf, lacc, 0, 0, 0);
#pragma unroll
      for (int di = 0; di < 4; ++di) {
        const short8 vf = *(const short8*)&Vs[buf][vo[ks] + di * 1024];
        oacc[di] = __builtin_amdgcn_mfma_f32_16x16x32_bf16(vf, pf, oacc[di], 0, 0, 0);
      }
    }
    __builtin_amdgcn_s_setprio(0);
    bar();  // all waves done reading buf before it+2's DMA can touch it
  }

  // all-ones A => every C row/reg of lacc equals l(q=lr)
  const float inv = 1.f / lacc[0];

  const int q = q0 + qrow;
#pragma unroll
  for (int di = 0; di < 4; ++di) {
    short4v o;
#pragma unroll
    for (int t = 0; t < 4; ++t) o[t] = f2bf(oacc[di][t] * inv);
    *(short4v*)&Ctx[(long)(b * S + q) * 2048 + h * 64 + di * 16 + g * 4] = o;
  }
}

// ---------------------------------------------------------------------------
extern "C" void kernel_launch(void* const* d_in, const int* in_sizes, int n_in,
                              void* d_out, int out_size, void* d_ws, size_t ws_size,
                              hipStream_t stream) {
  (void)in_sizes; (void)n_in; (void)out_size; (void)ws_size;
  const float* X    = (const float*)d_in[0];
  const float* cosp = (const float*)d_in[2];
  const float* sinp = (const float*)d_in[3];
  const float* Wq   = (const float*)d_in[4];
  const float* Wk   = (const float*)d_in[5];
  const float* Wv   = (const float*)d_in[6];
  const float* Wo   = (const float*)d_in[7];
  float* out = (float*)d_out;
  char* ws = (char*)d_ws;

  short* Xb = (short*)(ws + 0);           // 16.8 MB bf16 X
  short* WT = (short*)(ws + 16777216);    // 12.6 MB fused QKV^T; reused for Wo^T
  short* Y  = (short*)(ws + 29360128);    // 16.8 MB Ctx (attn out)
  short* Qr = (short*)(ws + 46137344);    // 16.8 MB rope'd Q
  short* Kr = (short*)(ws + 62914560);    // 4.2 MB rope'd K
  short* YV = (short*)(ws + 67108864);    // 4.2 MB compact V (B,S,512)
  short* Vt = (short*)(ws + 71303168);    // 4.2 MB  (total 75.5 MB)

  f32_to_bf16<<<4096, 256, 0, stream>>>(X, Xb);
  // fused QKV^T: rows [0,2048)=Wq^T, [2048,2560)=Wk^T, [2560,3072)=Wv^T
  wtrans3<<<dim3(32, 32, 3), 256, 0, stream>>>(Wq, Wk, Wv, WT);

  // fused QKV projection + RoPE + layout: writes Qr, Kr, YV directly
  gemm_bt<1><<<dim3(24, 32), 256, 0, stream>>>(
      Xb, WT, nullptr, Qr, Kr, YV, cosp, sinp, 4096, 3072, 2048);

  // Wo^T reuses WT (QKV GEMM already consumed it in stream order)
  transpose_f2b<<<dim3(32, 32), 256, 0, stream>>>(Wo, WT, 2048, 2048);

  // V (B,S,512) -> Vt (B,G,64,S)
  vtrans<<<dim3(32, 16), 256, 0, stream>>>(YV, Vt, 512, 0);

  // attention -> Ctx (Y)
  attn_kernel<<<dim3(16, 64), 512, 0, stream>>>(Qr, Kr, Vt, Y);

  // output projection (fp32 out)
  gemm_bt<2><<<dim3(16, 32), 256, 0, stream>>>(
      Y, WT, out, nullptr, nullptr, nullptr, nullptr, nullptr, 4096, 2048, 2048);
}

// Round 7
// 355.373 us; speedup vs baseline: 1.0873x; 1.0423x over previous
//
#include <hip/hip_runtime.h>
#include <stdint.h>

typedef __attribute__((ext_vector_type(8))) short short8;
typedef __attribute__((ext_vector_type(4))) short short4v;
typedef __attribute__((ext_vector_type(4))) float float4v;
typedef __attribute__((ext_vector_type(2))) unsigned uint2v;

__device__ __forceinline__ float bf2f(short s) {
  union { unsigned u; float f; } x;
  x.u = ((unsigned)(unsigned short)s) << 16;
  return x.f;
}
__device__ __forceinline__ short f2bf(float f) {
  union { float f; unsigned u; } x;
  x.f = f;
  unsigned r = x.u + 0x7fffu + ((x.u >> 16) & 1u);
  return (short)(r >> 16);
}
// bare v_exp_f32 — exp2f() calls __ocml_exp2_f32 (range/denorm fixups, ~30
// VALU); our scores are bounded |s|<~50 so the raw HW op is exact.
__device__ __forceinline__ float fexp2(float x) {
#if __has_builtin(__builtin_amdgcn_exp2f)
  return __builtin_amdgcn_exp2f(x);
#else
  float r;
  asm("v_exp_f32 %0, %1" : "=v"(r) : "v"(x));
  return r;
#endif
}
__device__ __forceinline__ void glds16(const void* g, void* l) {
  __builtin_amdgcn_global_load_lds(
      (const __attribute__((address_space(1))) void*)g,
      (__attribute__((address_space(3))) void*)l, 16, 0, 0);
}
__device__ __forceinline__ void bar() { __builtin_amdgcn_s_barrier(); }

// ---------------------------------------------------------------------------
// fp32 transpose -> bf16: src (R x C, f32) -> dst (C x R, bf16), 64x64 tiles.
// ---------------------------------------------------------------------------
__device__ __forceinline__ void transpose_tile(
    const float* __restrict__ src, short* __restrict__ dst, int R, int C,
    int r0, int c0) {
  __shared__ short t[64 * 72];
  const int tid = threadIdx.x;
#pragma unroll
  for (int r = 0; r < 2; ++r) {
    int c = r * 256 + tid;
    int row = c >> 3, col8 = (c & 7) * 8;
    const float4v a = *(const float4v*)&src[(long)(r0 + row) * C + c0 + col8];
    const float4v b = *(const float4v*)&src[(long)(r0 + row) * C + c0 + col8 + 4];
    short8 v;
#pragma unroll
    for (int e = 0; e < 4; ++e) { v[e] = f2bf(a[e]); v[e + 4] = f2bf(b[e]); }
    *(short8*)&t[row * 72 + col8] = v;
  }
  __syncthreads();
#pragma unroll
  for (int r = 0; r < 2; ++r) {
    int c = r * 256 + tid;
    int orow = c >> 3, ocol8 = (c & 7) * 8;
    short8 w;
#pragma unroll
    for (int e = 0; e < 8; ++e) w[e] = t[(ocol8 + e) * 72 + orow];
    *(short8*)&dst[(long)(c0 + orow) * R + r0 + ocol8] = w;
  }
}

// ---------------------------------------------------------------------------
// Fused preprocessing: blocks [0,4096) X f32->bf16; [4096,7168) QKV W^T.
// ---------------------------------------------------------------------------
__global__ __launch_bounds__(256) void prep(
    const float* __restrict__ X, short* __restrict__ Xb,
    const float* __restrict__ Wq, const float* __restrict__ Wk,
    const float* __restrict__ Wv, short* __restrict__ WT) {
  const int id = blockIdx.x;
  if (id < 4096) {
    const long i = ((long)id * 256 + threadIdx.x) * 8;
    const float4v a = *(const float4v*)&X[i];
    const float4v b = *(const float4v*)&X[i + 4];
    short8 v;
#pragma unroll
    for (int e = 0; e < 4; ++e) { v[e] = f2bf(a[e]); v[e + 4] = f2bf(b[e]); }
    *(short8*)&Xb[i] = v;
  } else {
    const int r = id - 4096;
    const int z = r >> 10, bx = r & 31, by = (r >> 5) & 31;
    const float* src = z == 0 ? Wq : (z == 1 ? Wk : Wv);
    const int C = z == 0 ? 2048 : 512;
    if (bx * 64 < C) {
      short* dst = WT + (z == 0 ? 0 : (z == 1 ? 2048 * 2048 : 2560 * 2048));
      transpose_tile(src, dst, 2048, C, by * 64, bx * 64);
    }
  }
}

__global__ __launch_bounds__(256) void transpose_f2b(
    const float* __restrict__ src, short* __restrict__ dst, int R, int C) {
  transpose_tile(src, dst, R, C, blockIdx.y * 64, blockIdx.x * 64);
}

// ---------------------------------------------------------------------------
// V reshape+transpose: YV (B,S,ld) cols [col0, col0+512) bf16 -> Vt (B,G,64,S).
// grid: (S/64, B*G)
// ---------------------------------------------------------------------------
__global__ __launch_bounds__(256) void vtrans(const short* __restrict__ Y,
                                              short* __restrict__ Vt,
                                              int ld, int col0) {
  const int bg = blockIdx.y;
  const int b = bg >> 3, gk = bg & 7;
  const int s0 = blockIdx.x * 64;
  __shared__ short t[64 * 72];
  const int tid = threadIdx.x;
#pragma unroll
  for (int r = 0; r < 2; ++r) {
    int c = r * 256 + tid;
    int row = c >> 3, col8 = (c & 7) * 8;
    short8 v = *(const short8*)&Y[(long)(b * 2048 + s0 + row) * ld + col0 + gk * 64 + col8];
    *(short8*)&t[row * 72 + col8] = v;
  }
  __syncthreads();
#pragma unroll
  for (int r = 0; r < 2; ++r) {
    int c = r * 256 + tid;
    int d = c >> 3, s8 = (c & 7) * 8;
    short8 w;
#pragma unroll
    for (int e = 0; e < 8; ++e) w[e] = t[(s8 + e) * 72 + d];
    *(short8*)&Vt[((long)bg * 64 + d) * 2048 + s0 + s8] = w;
  }
}

// ---------------------------------------------------------------------------
// GEMM: C (MxN) = A (MxK,bf16) * BT (NxK,bf16)^T. 128x128 tile, 4 waves.
// r0-proven structure and block mapping.
// MODE 1: fused RoPE/layout epilogue (head = 64-col wave strip):
//   h<32: RoPE+scale -> Qr (B,32,S,64); 32<=h<40: RoPE -> Kr (B,8,S,64);
//   h>=40: plain bf16 -> YV (B,S,512). Rope pair = acc[i][j] / acc[i][j+2].
// MODE 2: plain f32 store.
// ---------------------------------------------------------------------------
template <int MODE>
__global__ __launch_bounds__(256) void gemm_bt(
    const short* __restrict__ A, const short* __restrict__ BT,
    float* __restrict__ Cf, short* __restrict__ Qr, short* __restrict__ Kr,
    short* __restrict__ YV, const float* __restrict__ cosp,
    const float* __restrict__ sinp, int M, int N, int K) {
  (void)M;
  __shared__ short As[128 * 32];
  __shared__ short Bs[128 * 32];
  const int tid = threadIdx.x;
  const int wave = tid >> 6, lane = tid & 63;
  const int g = lane >> 4, lr = lane & 15;
  const int wr = wave >> 1, wc = wave & 1;
  const int m0 = blockIdx.y << 7, n0 = blockIdx.x << 7;

  float4v acc[4][4];
#pragma unroll
  for (int i = 0; i < 4; ++i)
#pragma unroll
    for (int j = 0; j < 4; ++j) acc[i][j] = (float4v)0.f;

  for (int kt = 0; kt < K; kt += 32) {
#pragma unroll
    for (int r = 0; r < 2; ++r) {
      const int cb = r * 256 + wave * 64;
      const int c = cb + lane;
      const int row = c >> 2, kc = c & 3;
      glds16(A + (long)(m0 + row) * K + kt + kc * 8, As + cb * 8);
      glds16(BT + (long)(n0 + row) * K + kt + kc * 8, Bs + cb * 8);
    }
    __syncthreads();
    short8 af[4], bfr[4];
#pragma unroll
    for (int i = 0; i < 4; ++i)
      af[i] = *(const short8*)&As[(wr * 64 + i * 16 + lr) * 32 + g * 8];
#pragma unroll
    for (int j = 0; j < 4; ++j)
      bfr[j] = *(const short8*)&Bs[(wc * 64 + j * 16 + lr) * 32 + g * 8];
#pragma unroll
    for (int i = 0; i < 4; ++i)
#pragma unroll
      for (int j = 0; j < 4; ++j)
        acc[i][j] = __builtin_amdgcn_mfma_f32_16x16x32_bf16(af[i], bfr[j], acc[i][j], 0, 0, 0);
    __syncthreads();
  }

  if constexpr (MODE == 1) {
    const int h = (n0 + wc * 64) >> 6;  // head index in [0,48)
#pragma unroll
    for (int i = 0; i < 4; ++i)
#pragma unroll
      for (int t = 0; t < 4; ++t) {
        const int r = m0 + wr * 64 + i * 16 + g * 4 + t;
        const int s = r & 2047, bb = r >> 11;
        if (h < 40) {
          const float sc = h < 32 ? 0.18033688011112043f : 1.0f;
          short* base = h < 32
              ? Qr + ((long)(bb * 32 + h) * 2048 + s) * 64
              : Kr + ((long)(bb * 8 + (h - 32)) * 2048 + s) * 64;
          const float* cr = cosp + s * 64;
          const float* sr = sinp + s * 64;
#pragma unroll
          for (int j = 0; j < 2; ++j) {
            const int d = j * 16 + lr;
            const float x1 = acc[i][j][t];
            const float x2 = acc[i][j + 2][t];
            base[d] = f2bf((x1 * cr[d] - x2 * sr[d]) * sc);
            base[d + 32] = f2bf((x2 * cr[d + 32] + x1 * sr[d + 32]) * sc);
          }
        } else {
          short* base = YV + ((long)bb * 2048 + s) * 512 + (h - 40) * 64;
#pragma unroll
          for (int j = 0; j < 4; ++j) base[j * 16 + lr] = f2bf(acc[i][j][t]);
        }
      }
  } else {
#pragma unroll
    for (int i = 0; i < 4; ++i)
#pragma unroll
      for (int j = 0; j < 4; ++j)
#pragma unroll
        for (int t = 0; t < 4; ++t) {
          const int r = m0 + wr * 64 + i * 16 + g * 4 + t;
          const int cc = n0 + wc * 64 + j * 16 + lr;
          Cf[(long)r * N + cc] = acc[i][j][t];
        }
  }
}

// ---------------------------------------------------------------------------
// Flash attention, transposed formulation, fixed-shift softmax.
// Qr (B,H,S,64) pre-scaled by log2(e)/8, Kr (B,G,S,64), Vt (B,G,64,S).
// Block: 512 thr (8 waves), TWO 128-q tiles per block (QBLK=256) x full S:
//   grid (8,64) = 512 blocks = exactly 2/CU -> single residency pass, no
//   tail; K/V staged once per iter feeds both q-halves (2x barrier/DMA
//   amortization, 1/2 K/V cache traffic). K-fragments register-hoisted
//   (q-independent). KVBLK=64, dbuf staging, counted vmcnt(2). LDS 48 KiB.
//   P-pack via the r5-proven perm trick (round-half-up + v_perm_b32) —
//   cvt_pk_bf16 REVERTED (r6 bisect: only unverified-semantics instr in the
//   failing bundle).
// ---------------------------------------------------------------------------
__global__ __launch_bounds__(512, 4) void attn_kernel(
    const short* __restrict__ Qr, const short* __restrict__ Kr,
    const short* __restrict__ Vt, short* __restrict__ Ctx) {
  constexpr int S = 2048;
  constexpr int NIT = 32;
  const int bh = blockIdx.y;
  const int b = bh >> 5, h = bh & 31;
  const int gk = h >> 2;
  const int q0 = blockIdx.x << 8;  // 256 q rows per block
  const int tid = threadIdx.x;
  const int w = tid >> 6, lane = tid & 63;
  const int g = lane >> 4, lr = lane & 15;
  const int b8 = lr & 7;
  const int qrow = w * 16 + lr;

  __shared__ short Ks[2][64 * 64];  // [buf][kv][d], granule swizzle by kv&7
  __shared__ short Vs[2][64 * 64];  // [buf][d][kv], granule swizzle by d&7
  __shared__ short Ps[128 * 64];    // [q][kv],      granule swizzle by q&7

  const short* Qb = Qr + (long)(b * 32 + h) * S * 64;
  const short* Kb = Kr + (long)(b * 8 + gk) * S * 64;
  const short* Vb = Vt + (long)(b * 8 + gk) * 64 * S;

  // LDS read element-offsets
  const int ko0 = lr * 64 + ((0 + g) ^ b8) * 8;  // Ks, kk=0; +i*1024, i<4
  const int ko1 = lr * 64 + ((4 + g) ^ b8) * 8;  // Ks, kk=1
  int vo[2], pr[2], pw[4];
#pragma unroll
  for (int ks = 0; ks < 2; ++ks) {
    vo[ks] = lr * 64 + ((ks * 4 + g) ^ b8) * 8;    // Vs; +di*1024
    pr[ks] = qrow * 64 + ((ks * 4 + g) ^ b8) * 8;  // Ps read
  }
#pragma unroll
  for (int i = 0; i < 4; ++i)
    pw[i] = qrow * 64 + ((2 * i + (g >> 1)) ^ b8) * 8 + (g & 1) * 4;

  // staging: one glds16 each for K and V per iteration (8 KB each).
  const int srow = tid >> 3, sl = tid & 7;
  const long koff = (long)srow * 64 + (sl ^ (srow & 7)) * 8;
  const long voff = (long)srow * S + (sl ^ (srow & 7)) * 8;

  short8 qf[2][2];
#pragma unroll
  for (int qh = 0; qh < 2; ++qh) {
    qf[qh][0] = *(const short8*)&Qb[(long)(q0 + qh * 128 + qrow) * 64 + g * 8];
    qf[qh][1] = *(const short8*)&Qb[(long)(q0 + qh * 128 + qrow) * 64 + 32 + g * 8];
  }

  const short8 ones = (short8)(short)0x3F80;  // bf16 1.0 x8
  float4v lacc[2];
  float4v oacc[2][4];
#pragma unroll
  for (int qh = 0; qh < 2; ++qh) {
    lacc[qh] = (float4v)0.f;
#pragma unroll
    for (int di = 0; di < 4; ++di) oacc[qh][di] = (float4v)0.f;
  }

  // prologue: stage it 0 into buf 0
  glds16(Kb + koff, &Ks[0][w * 512]);
  glds16(Vb + voff, &Vs[0][w * 512]);

  for (int it = 0; it < NIT; ++it) {
    const int buf = it & 1;
    if (it + 1 < NIT) {
      glds16(Kb + (long)(it + 1) * 64 * 64 + koff, &Ks[buf ^ 1][w * 512]);
      glds16(Vb + (it + 1) * 64 + voff, &Vs[buf ^ 1][w * 512]);
      asm volatile("s_waitcnt vmcnt(2)" ::: "memory");  // it's 2 landed
    } else {
      asm volatile("s_waitcnt vmcnt(0)" ::: "memory");
    }
    __builtin_amdgcn_sched_barrier(0);
    bar();

    // K fragments are q-independent: hoist once, reuse for both q-halves.
    short8 kf[8];
#pragma unroll
    for (int i = 0; i < 4; ++i) {
      kf[i] = *(const short8*)&Ks[buf][ko0 + i * 1024];
      kf[4 + i] = *(const short8*)&Ks[buf][ko1 + i * 1024];
    }

#pragma unroll
    for (int qh = 0; qh < 2; ++qh) {
      // S^T tile: rows = kv (64), cols = q (wave strip of 16)
      float4v sacc[4];
#pragma unroll
      for (int i = 0; i < 4; ++i) sacc[i] = (float4v)0.f;
      __builtin_amdgcn_s_setprio(1);
#pragma unroll
      for (int i = 0; i < 4; ++i)
        sacc[i] = __builtin_amdgcn_mfma_f32_16x16x32_bf16(kf[i], qf[qh][0], sacc[i], 0, 0, 0);
#pragma unroll
      for (int i = 0; i < 4; ++i)
        sacc[i] = __builtin_amdgcn_mfma_f32_16x16x32_bf16(kf[4 + i], qf[qh][1], sacc[i], 0, 0, 0);
      __builtin_amdgcn_s_setprio(0);

      // fixed-shift softmax: p = exp2(s) (bare v_exp_f32), pack bf16 -> Ps
      // (r5-proven round-half-up + v_perm_b32 pack)
#pragma unroll
      for (int i = 0; i < 4; ++i) {
        union { float f; unsigned u; } a0, a1, a2, a3;
        a0.f = fexp2(sacc[i][0]);
        a1.f = fexp2(sacc[i][1]);
        a2.f = fexp2(sacc[i][2]);
        a3.f = fexp2(sacc[i][3]);
        const unsigned d0 = __builtin_amdgcn_perm(a1.u + 0x8000u, a0.u + 0x8000u, 0x07060302u);
        const unsigned d1 = __builtin_amdgcn_perm(a3.u + 0x8000u, a2.u + 0x8000u, 0x07060302u);
        *(uint2v*)&Ps[pw[i]] = (uint2v){d0, d1};
      }

      // O^T += V^T * P^T; l += 1^T * P^T (Ps rows wave-private; no barrier)
      __builtin_amdgcn_s_setprio(1);
#pragma unroll
      for (int ks = 0; ks < 2; ++ks) {
        const short8 pf = *(const short8*)&Ps[pr[ks]];
        lacc[qh] = __builtin_amdgcn_mfma_f32_16x16x32_bf16(ones, pf, lacc[qh], 0, 0, 0);
#pragma unroll
        for (int di = 0; di < 4; ++di) {
          const short8 vf = *(const short8*)&Vs[buf][vo[ks] + di * 1024];
          oacc[qh][di] = __builtin_amdgcn_mfma_f32_16x16x32_bf16(vf, pf, oacc[qh][di], 0, 0, 0);
        }
      }
      __builtin_amdgcn_s_setprio(0);
    }
    bar();  // all waves done reading buf before it+2's DMA can touch it
  }

  // all-ones A => every C row/reg of lacc equals l(q)
#pragma unroll
  for (int qh = 0; qh < 2; ++qh) {
    const float inv = 1.f / lacc[qh][0];
    const int q = q0 + qh * 128 + qrow;
#pragma unroll
    for (int di = 0; di < 4; ++di) {
      short4v o;
#pragma unroll
      for (int t = 0; t < 4; ++t) o[t] = f2bf(oacc[qh][di][t] * inv);
      *(short4v*)&Ctx[(long)(b * S + q) * 2048 + h * 64 + di * 16 + g * 4] = o;
    }
  }
}

// ---------------------------------------------------------------------------
extern "C" void kernel_launch(void* const* d_in, const int* in_sizes, int n_in,
                              void* d_out, int out_size, void* d_ws, size_t ws_size,
                              hipStream_t stream) {
  (void)in_sizes; (void)n_in; (void)out_size; (void)ws_size;
  const float* X    = (const float*)d_in[0];
  const float* cosp = (const float*)d_in[2];
  const float* sinp = (const float*)d_in[3];
  const float* Wq   = (const float*)d_in[4];
  const float* Wk   = (const float*)d_in[5];
  const float* Wv   = (const float*)d_in[6];
  const float* Wo   = (const float*)d_in[7];
  float* out = (float*)d_out;
  char* ws = (char*)d_ws;

  short* Xb = (short*)(ws + 0);           // 16.8 MB bf16 X
  short* WT = (short*)(ws + 16777216);    // 12.6 MB fused QKV^T; reused for Wo^T
  short* Y  = (short*)(ws + 29360128);    // 16.8 MB Ctx (attn out)
  short* Qr = (short*)(ws + 46137344);    // 16.8 MB rope'd Q
  short* Kr = (short*)(ws + 62914560);    // 4.2 MB rope'd K
  short* YV = (short*)(ws + 67108864);    // 4.2 MB compact V (B,S,512)
  short* Vt = (short*)(ws + 71303168);    // 4.2 MB  (total 75.5 MB)

  // fused: X -> bf16 (blocks 0..4095) + QKV W^T (blocks 4096..7167)
  prep<<<7168, 256, 0, stream>>>(X, Xb, Wq, Wk, Wv, WT);

  // fused QKV projection + RoPE + layout: writes Qr, Kr, YV directly
  gemm_bt<1><<<dim3(24, 32), 256, 0, stream>>>(
      Xb, WT, nullptr, Qr, Kr, YV, cosp, sinp, 4096, 3072, 2048);

  // Wo^T reuses WT (QKV GEMM already consumed it in stream order)
  transpose_f2b<<<dim3(32, 32), 256, 0, stream>>>(Wo, WT, 2048, 2048);

  // V (B,S,512) -> Vt (B,G,64,S)
  vtrans<<<dim3(32, 16), 256, 0, stream>>>(YV, Vt, 512, 0);

  // attention -> Ctx (Y); 512 blocks = 2/CU exactly (QBLK=256)
  attn_kernel<<<dim3(8, 64), 512, 0, stream>>>(Qr, Kr, Vt, Y);

  // output projection (fp32 out)
  gemm_bt<2><<<dim3(16, 32), 256, 0, stream>>>(
      Y, WT, out, nullptr, nullptr, nullptr, nullptr, nullptr, 4096, 2048, 2048);
}